// Round 15
// baseline (174.411 us; speedup 1.0000x reference)
//
#include <hip/hip_runtime.h>
#include <math.h>

// Sizes: N=2000, M=32, H=64, EMB=32, F=32, T=12, B=4, HOR=12, K=2, DILS=(1,2)

// ---------------- K1: node MLP -> q, ek, nh2; also xT, TCN W2 pack, SAGE wpack ----
__global__ __launch_bounds__(256) void k_embed(
    const float* __restrict__ nf, const float* __restrict__ inputs,
    const float* __restrict__ w3, const float* __restrict__ b3,
    const float* __restrict__ w4, const float* __restrict__ b4,
    const float* __restrict__ w5, const float* __restrict__ b5,
    const float* __restrict__ wq, const float* __restrict__ wk,
    const float* __restrict__ wn, const float* __restrict__ bn,
    const float* __restrict__ b_in,
    const float* __restrict__ tw1, const float* __restrict__ tw2,
    const float* __restrict__ sws, const float* __restrict__ swn,
    float2* __restrict__ W2, float4* __restrict__ wsg,
    float* __restrict__ qo, float* __restrict__ eko, float* __restrict__ nho,
    float* __restrict__ xT)
{
    const int tid = threadIdx.x;
    if (tid < 192) {                                   // xT transpose: 500*192 = 96000
        const int id = blockIdx.x * 192 + tid;
        const int t = id / 8000, rem = id % 8000;
        const int b = rem / 2000, n2 = rem % 2000;
        xT[n2 * 48 + b * 12 + t] = inputs[id];
    }
    if (blockIdx.x < 64) {            // TCN weights -> [c][ig][o][ii]{k0,k1}, 16384 f2
        const int id = blockIdx.x * 256 + tid;
        const int c = id >> 12, r = id & 4095;
        const int ig = r >> 8, o = (r >> 2) & 63, ii = r & 3;
        const float* src = (c == 0) ? tw1 : (c == 1) ? tw2
                         : (c == 2) ? tw1 + 8192 : tw2 + 8192;
        const int i = ig * 4 + ii;
        W2[id] = make_float2(src[o * 128 + i * 2], src[o * 128 + i * 2 + 1]);
    } else if (blockIdx.x < 80) {                      // SAGE weights -> [l][k2][h] float4
        const int id = (blockIdx.x - 64) * 256 + tid;  // 0..4095
        const int l = id >> 11, rr = id & 2047;
        const int k2 = rr >> 6, h = rr & 63;
        const float* S = sws + l * 4096;
        const float* Nn = swn + l * 4096;
        wsg[id] = make_float4(S[(2 * k2) * 64 + h],     Nn[(2 * k2) * 64 + h],
                              S[(2 * k2 + 1) * 64 + h], Nn[(2 * k2 + 1) * 64 + h]);
    }
    const int lane = tid & 63;
    const int n = blockIdx.x * 4 + (tid >> 6);

    float nfv = 0.f;
    if (lane < 32) nfv = nf[n * 32 + lane];

    float e1 = b3[lane];
#pragma unroll
    for (int f = 0; f < 32; ++f)
        e1 = fmaf(__shfl(nfv, f), w3[f * 64 + lane], e1);
    e1 = fmaxf(e1, 0.f);

    float e2 = b4[lane];
#pragma unroll
    for (int f = 0; f < 64; ++f)
        e2 = fmaf(__shfl(e1, f), w4[f * 64 + lane], e2);
    e2 = fmaxf(e2, 0.f);

    const int c = lane & 31;
    float ev = b5[c];
#pragma unroll
    for (int f = 0; f < 64; ++f)
        ev = fmaf(__shfl(e2, f), w5[f * 32 + c], ev);

    float qv = 0.f, ekv = 0.f, nhv = bn[lane] + b_in[lane];
#pragma unroll
    for (int f = 0; f < 32; ++f) {
        float e = __shfl(ev, f);
        qv  = fmaf(e, wq[f * 64 + lane], qv);
        ekv = fmaf(e, wk[f * 64 + lane], ekv);
        nhv = fmaf(e, wn[f * 64 + lane], nhv);
    }
    qo [n * 64 + lane] = qv;
    eko[n * 64 + lane] = ekv;
    nho[n * 64 + lane] = nhv;
}

// ---------------- K2: fused scores+softmax -> wadj; ax -> xa; base1 (+vecs) ----
__global__ __launch_bounds__(256) void k_front(
    const float* __restrict__ q, const float* __restrict__ ek,
    const float* __restrict__ xT, const float* __restrict__ nh2,
    const int* __restrict__ nidx,
    const float* __restrict__ sws, const float* __restrict__ sbs,
    const float* __restrict__ swn, const float* __restrict__ sbn,
    const float* __restrict__ w_in, const float4* __restrict__ wsg,
    float* __restrict__ wadj, float2* __restrict__ xa,
    float* __restrict__ base1, float* __restrict__ vecs)
{
    const int tid = threadIdx.x;
    const int lane = tid & 63, wave = tid >> 6;
    if (blockIdx.x == 500) {
        if (wave == 0) {
            const float wv = w_in[lane];
            float s1 = 0.f, n1 = 0.f;
#pragma unroll
            for (int k = 0; k < 64; ++k) {
                const float wkk = __shfl(wv, k);
                s1 = fmaf(wkk, sws[k * 64 + lane], s1);
                n1 = fmaf(wkk, swn[k * 64 + lane], n1);
            }
            vecs[lane] = s1; vecs[64 + lane] = n1;
        }
        return;
    }
    __shared__ __align__(16) float2 pair[4][64];
    const int n = blockIdx.x * 4 + wave;

    int j = 0;
    if (lane < 32) j = nidx[n * 32 + lane];
    float w;
    {
        const float4* qr = (const float4*)(q + n * 64);
        const float4* er = (const float4*)(ek + j * 64);
        float s = 0.f;
#pragma unroll
        for (int u = 0; u < 16; ++u) {
            const float4 a = qr[u], b = er[u];
            s = fmaf(a.x, b.x, s); s = fmaf(a.y, b.y, s);
            s = fmaf(a.z, b.z, s); s = fmaf(a.w, b.w, s);
        }
        s *= 0.125f;
        float mx = s;
#pragma unroll
        for (int d = 16; d >= 1; d >>= 1) mx = fmaxf(mx, __shfl_xor(mx, d));
        const float ex = expf(s - mx);
        float sum = ex;
#pragma unroll
        for (int d = 16; d >= 1; d >>= 1) sum += __shfl_xor(sum, d);
        w = ex / sum;
        if (lane < 32) wadj[n * 32 + lane] = w;
    }
    float ax = 0.f, anh = 0.f;
    const bool act = lane < 48;
#pragma unroll 8
    for (int m = 0; m < 32; ++m) {
        const int jm = __shfl(j, m);
        const float wm = __shfl(w, m);
        const float xv = act ? xT[jm * 48 + lane] : 0.f;
        ax  = fmaf(wm, xv, ax);
        anh = fmaf(wm, nh2[jm * 64 + lane], anh);
    }
    if (act) xa[n * 48 + lane] = make_float2(xT[n * 48 + lane], ax);
    pair[wave][lane] = make_float2(nh2[n * 64 + lane], anh);
    __syncthreads();

    float acc = sbs[lane] + sbn[lane];
    const float2* pw = pair[wave];
#pragma unroll
    for (int k2 = 0; k2 < 32; ++k2) {
        const float4 wv = wsg[k2 * 64 + lane];
        const float4 sv = *(const float4*)(pw + k2 * 2);
        acc = fmaf(sv.x, wv.x, acc); acc = fmaf(sv.y, wv.y, acc);
        acc = fmaf(sv.z, wv.z, acc); acc = fmaf(sv.w, wv.w, acc);
    }
    base1[n * 64 + lane] = acc;
}

// ---------------- K3: fused SAGE layer 2 (recompute h1 from scalars) -> mid ----------
__global__ __launch_bounds__(512, 8) void k_sage2(
    const float* __restrict__ base1, const float2* __restrict__ xa,
    const float* __restrict__ vecs,
    const int* __restrict__ nidx, const float* __restrict__ wadj,
    const float4* __restrict__ wsg2,
    const float* __restrict__ sbs, const float* __restrict__ sbn,
    float* __restrict__ mid)
{
    __shared__ __align__(16) float2 svp[48][64];        // {h1self, agg}, 24 KB
    const int tid = threadIdx.x, lane = tid & 63;
    const int wave = __builtin_amdgcn_readfirstlane(tid >> 6);
    const int n = blockIdx.x;
    const int bt0 = wave * 6;

    const float s1 = vecs[lane], n1 = vecs[64 + lane];
    const float bs = base1[n * 64 + lane];

    float agg[6] = {0.f, 0.f, 0.f, 0.f, 0.f, 0.f};
#pragma unroll 8
    for (int m = 0; m < 32; ++m) {
        const int j = nidx[n * 32 + m];                 // block-uniform -> s_load
        const float w = wadj[n * 32 + m];               // block-uniform -> s_load
        const float bj = base1[j * 64 + lane];
        const float4* xr = (const float4*)(xa + j * 48 + bt0);
        const float4 p0 = xr[0], p1 = xr[1], p2 = xr[2];
        float t;
        t = fmaf(p0.x, s1, fmaf(p0.y, n1, bj)); agg[0] = fmaf(w, fmaxf(t, 0.f), agg[0]);
        t = fmaf(p0.z, s1, fmaf(p0.w, n1, bj)); agg[1] = fmaf(w, fmaxf(t, 0.f), agg[1]);
        t = fmaf(p1.x, s1, fmaf(p1.y, n1, bj)); agg[2] = fmaf(w, fmaxf(t, 0.f), agg[2]);
        t = fmaf(p1.z, s1, fmaf(p1.w, n1, bj)); agg[3] = fmaf(w, fmaxf(t, 0.f), agg[3]);
        t = fmaf(p2.x, s1, fmaf(p2.y, n1, bj)); agg[4] = fmaf(w, fmaxf(t, 0.f), agg[4]);
        t = fmaf(p2.z, s1, fmaf(p2.w, n1, bj)); agg[5] = fmaf(w, fmaxf(t, 0.f), agg[5]);
    }
    {
        const float4* xs = (const float4*)(xa + n * 48 + bt0);
        const float4 q0 = xs[0], q1 = xs[1], q2 = xs[2];
        svp[bt0 + 0][lane] = make_float2(fmaxf(fmaf(q0.x, s1, fmaf(q0.y, n1, bs)), 0.f), agg[0]);
        svp[bt0 + 1][lane] = make_float2(fmaxf(fmaf(q0.z, s1, fmaf(q0.w, n1, bs)), 0.f), agg[1]);
        svp[bt0 + 2][lane] = make_float2(fmaxf(fmaf(q1.x, s1, fmaf(q1.y, n1, bs)), 0.f), agg[2]);
        svp[bt0 + 3][lane] = make_float2(fmaxf(fmaf(q1.z, s1, fmaf(q1.w, n1, bs)), 0.f), agg[3]);
        svp[bt0 + 4][lane] = make_float2(fmaxf(fmaf(q2.x, s1, fmaf(q2.y, n1, bs)), 0.f), agg[4]);
        svp[bt0 + 5][lane] = make_float2(fmaxf(fmaf(q2.z, s1, fmaf(q2.w, n1, bs)), 0.f), agg[5]);
    }
    const float b2 = sbs[64 + lane] + sbn[64 + lane];
    float acc[6] = {b2, b2, b2, b2, b2, b2};
    const float4* wp = wsg2 + lane;
    const float2* s0 = svp[bt0];
#pragma unroll
    for (int k2 = 0; k2 < 32; ++k2) {
        const float4 w4 = wp[k2 * 64];
        const float4 v0 = *(const float4*)(s0 + 0 * 64 + k2 * 2);
        const float4 v1 = *(const float4*)(s0 + 1 * 64 + k2 * 2);
        const float4 v2 = *(const float4*)(s0 + 2 * 64 + k2 * 2);
        const float4 v3 = *(const float4*)(s0 + 3 * 64 + k2 * 2);
        const float4 v4 = *(const float4*)(s0 + 4 * 64 + k2 * 2);
        const float4 v5 = *(const float4*)(s0 + 5 * 64 + k2 * 2);
        acc[0] = fmaf(v0.x, w4.x, fmaf(v0.y, w4.y, fmaf(v0.z, w4.z, fmaf(v0.w, w4.w, acc[0]))));
        acc[1] = fmaf(v1.x, w4.x, fmaf(v1.y, w4.y, fmaf(v1.z, w4.z, fmaf(v1.w, w4.w, acc[1]))));
        acc[2] = fmaf(v2.x, w4.x, fmaf(v2.y, w4.y, fmaf(v2.z, w4.z, fmaf(v2.w, w4.w, acc[2]))));
        acc[3] = fmaf(v3.x, w4.x, fmaf(v3.y, w4.y, fmaf(v3.z, w4.z, fmaf(v3.w, w4.w, acc[3]))));
        acc[4] = fmaf(v4.x, w4.x, fmaf(v4.y, w4.y, fmaf(v4.z, w4.z, fmaf(v4.w, w4.w, acc[4]))));
        acc[5] = fmaf(v5.x, w4.x, fmaf(v5.y, w4.y, fmaf(v5.z, w4.z, fmaf(v5.w, w4.w, acc[5]))));
    }
#pragma unroll
    for (int r = 0; r < 6; ++r)
        mid[((bt0 + r) * 2000 + n) * 64 + lane] = fmaxf(acc[r], 0.f);
}

// ---------------- K4: TCN seq-parallel GEMM, 256 thr / 4 waves / 8 seqs / 2 ch/lane ----
// block = 8 seqs; lane = (hg,s): s = seq (8), hg -> 2-ch subtile (8 groups);
// wave covers 16 out-ch (obase = wfl*16 + hg*2). 1000 blocks -> 8 blocks/CU,
// LDS 19.6 KB, VGPR <= 64 (same per-thread shape as r12's 52). Slot algebra
// identical to verified r11/r12: x1 t=5..11 -> slots 0..6; y1 -> {0,1,7,3,8,5};
// x2 -> {0,1,7}; y3 -> {3,8}; hs = slot 6.
__global__ __launch_bounds__(256, 8) void k_tcn(
    const float* __restrict__ mid, const float2* __restrict__ W2,
    const float* __restrict__ tb1, const float* __restrict__ tb2,
    const float* __restrict__ wgate, const float* __restrict__ bgate,
    const float* __restrict__ wout, const float* __restrict__ bout,
    float* __restrict__ outp)
{
    __shared__ __align__(16) float xls[9][8][68];        // 19.1 KB
    const int tid = threadIdx.x, lane = tid & 63;
    const int wfl = __builtin_amdgcn_readfirstlane(tid >> 6);   // 0..3
    const int hg = (lane >> 3) & 7;
    const int s = lane & 7;
    const int bI = blockIdx.x / 250;                     // 250 blocks per b (2000/8)
    const int n0 = (blockIdx.x - bI * 250) * 8;
    const long base = ((long)(bI * 12) * 2000 + n0) * 64;
    const int obase = wfl * 16 + hg * 2;                 // 2 ch per lane
    const float4* __restrict__ Wf4 = (const float4*)W2;  // [(c*16+ig)*64+o]*2 {+0,+1}

    // ---- stage 0: stage x1[t=5..11] -> slots 0..6, layout [slot][s][ch]
    for (int e = tid; e < 896; e += 256) {
        const int u = e >> 7, rem = e & 127;
        const int ss = rem >> 4, qq = rem & 15;
        const float4 v = *(const float4*)(mid + base + (5 + u) * 128000L + ss * 64 + qq * 4);
        *(float4*)&xls[u][ss][qq * 4] = v;
    }
    __syncthreads();

    // ---- stage 1: l0 conv1 (D=1): y1[t=6..11]
    float y[2][6];
    {
        const float2 bv = *(const float2*)(tb1 + obase);
#pragma unroll
        for (int j = 0; j < 6; ++j) { y[0][j] = bv.x; y[1][j] = bv.y; }
    }
#pragma unroll 2
    for (int ig = 0; ig < 16; ++ig) {
        float4 xv[7];
#pragma unroll
        for (int u = 0; u < 7; ++u)
            xv[u] = *(const float4*)&xls[u][s][ig * 4];
#pragma unroll
        for (int oo = 0; oo < 2; ++oo) {
            const float4 wA = Wf4[(ig * 64 + obase + oo) * 2 + 0];
            const float4 wB = Wf4[(ig * 64 + obase + oo) * 2 + 1];
#pragma unroll
            for (int j = 0; j < 6; ++j) {
                float acc = y[oo][j];
                acc = fmaf(wA.x, xv[j].x, acc); acc = fmaf(wA.y, xv[j+1].x, acc);
                acc = fmaf(wA.z, xv[j].y, acc); acc = fmaf(wA.w, xv[j+1].y, acc);
                acc = fmaf(wB.x, xv[j].z, acc); acc = fmaf(wB.y, xv[j+1].z, acc);
                acc = fmaf(wB.z, xv[j].w, acc); acc = fmaf(wB.w, xv[j+1].w, acc);
                y[oo][j] = acc;
            }
        }
    }
    __syncthreads();                                     // all stage-1 reads done
    // y1 -> slots {0,1,7,3,8,5} (x1 slots 2,4,6 = residuals preserved)
    {
        const int S1OUT[6] = {0, 1, 7, 3, 8, 5};
#pragma unroll
        for (int j = 0; j < 6; ++j) {
            float2 o2;
            o2.x = fmaxf(y[0][j], 0.f); o2.y = fmaxf(y[1][j], 0.f);
            *(float2*)&xls[S1OUT[j]][s][obase] = o2;
        }
    }
    __syncthreads();

    // ---- stage 2: l0 conv2 (D=1) at t=7,9,11
    float a[2][3];
    {
        const float2 bv = *(const float2*)(tb2 + obase);
#pragma unroll
        for (int v = 0; v < 3; ++v) { a[0][v] = bv.x; a[1][v] = bv.y; }
    }
#pragma unroll 2
    for (int ig = 0; ig < 16; ++ig) {
        const float4 y0 = *(const float4*)&xls[0][s][ig * 4];   // y1@6
        const float4 y1v = *(const float4*)&xls[1][s][ig * 4];  // y1@7
        const float4 y2 = *(const float4*)&xls[7][s][ig * 4];   // y1@8
        const float4 y3v = *(const float4*)&xls[3][s][ig * 4];  // y1@9
        const float4 y4 = *(const float4*)&xls[8][s][ig * 4];   // y1@10
        const float4 y5 = *(const float4*)&xls[5][s][ig * 4];   // y1@11
#pragma unroll
        for (int oo = 0; oo < 2; ++oo) {
            const float4 wA = Wf4[((16 + ig) * 64 + obase + oo) * 2 + 0];
            const float4 wB = Wf4[((16 + ig) * 64 + obase + oo) * 2 + 1];
            float t0 = a[oo][0], t1 = a[oo][1], t2 = a[oo][2];
            t0 = fmaf(wA.x, y0.x, t0);  t0 = fmaf(wA.y, y1v.x, t0);
            t0 = fmaf(wA.z, y0.y, t0);  t0 = fmaf(wA.w, y1v.y, t0);
            t0 = fmaf(wB.x, y0.z, t0);  t0 = fmaf(wB.y, y1v.z, t0);
            t0 = fmaf(wB.z, y0.w, t0);  t0 = fmaf(wB.w, y1v.w, t0);
            t1 = fmaf(wA.x, y2.x, t1);  t1 = fmaf(wA.y, y3v.x, t1);
            t1 = fmaf(wA.z, y2.y, t1);  t1 = fmaf(wA.w, y3v.y, t1);
            t1 = fmaf(wB.x, y2.z, t1);  t1 = fmaf(wB.y, y3v.z, t1);
            t1 = fmaf(wB.z, y2.w, t1);  t1 = fmaf(wB.w, y3v.w, t1);
            t2 = fmaf(wA.x, y4.x, t2);  t2 = fmaf(wA.y, y5.x, t2);
            t2 = fmaf(wA.z, y4.y, t2);  t2 = fmaf(wA.w, y5.y, t2);
            t2 = fmaf(wB.x, y4.z, t2);  t2 = fmaf(wB.y, y5.z, t2);
            t2 = fmaf(wB.z, y4.w, t2);  t2 = fmaf(wB.w, y5.w, t2);
            a[oo][0] = t0; a[oo][1] = t1; a[oo][2] = t2;
        }
    }
    __syncthreads();                                     // stage-2 reads done
    // x2[t] = relu(relu(a) + x1[t]) -> slots {0,1,7}; residuals slots {2,4,6}
    {
        const int RIN[3] = {2, 4, 6}, ROUT[3] = {0, 1, 7};
#pragma unroll
        for (int v = 0; v < 3; ++v) {
            const float2 xr = *(const float2*)&xls[RIN[v]][s][obase];
            float2 o2;
            o2.x = fmaxf(fmaxf(a[0][v], 0.f) + xr.x, 0.f);
            o2.y = fmaxf(fmaxf(a[1][v], 0.f) + xr.y, 0.f);
            *(float2*)&xls[ROUT[v]][s][obase] = o2;
        }
    }
    __syncthreads();

    // ---- stage 3: l1 conv1 (D=2) at t=9,11; x2 slots {0,1,7}
    float d[2][2];
    {
        const float2 bv = *(const float2*)(tb1 + 64 + obase);
        d[0][0] = bv.x; d[0][1] = bv.x; d[1][0] = bv.y; d[1][1] = bv.y;
    }
#pragma unroll 2
    for (int ig = 0; ig < 16; ++ig) {
        const float4 x0 = *(const float4*)&xls[0][s][ig * 4];   // x2@7
        const float4 x1 = *(const float4*)&xls[1][s][ig * 4];   // x2@9
        const float4 x2 = *(const float4*)&xls[7][s][ig * 4];   // x2@11
#pragma unroll
        for (int oo = 0; oo < 2; ++oo) {
            const float4 wA = Wf4[((32 + ig) * 64 + obase + oo) * 2 + 0];
            const float4 wB = Wf4[((32 + ig) * 64 + obase + oo) * 2 + 1];
            float t0 = d[oo][0], t1 = d[oo][1];
            t0 = fmaf(wA.x, x0.x, t0);  t0 = fmaf(wA.y, x1.x, t0);
            t0 = fmaf(wA.z, x0.y, t0);  t0 = fmaf(wA.w, x1.y, t0);
            t0 = fmaf(wB.x, x0.z, t0);  t0 = fmaf(wB.y, x1.z, t0);
            t0 = fmaf(wB.z, x0.w, t0);  t0 = fmaf(wB.w, x1.w, t0);
            t1 = fmaf(wA.x, x1.x, t1);  t1 = fmaf(wA.y, x2.x, t1);
            t1 = fmaf(wA.z, x1.y, t1);  t1 = fmaf(wA.w, x2.y, t1);
            t1 = fmaf(wB.x, x1.z, t1);  t1 = fmaf(wB.y, x2.z, t1);
            t1 = fmaf(wB.z, x1.w, t1);  t1 = fmaf(wB.w, x2.w, t1);
            d[oo][0] = t0; d[oo][1] = t1;
        }
    }
    // y3 -> slots {3,8} (y1 dead; stage-3 reads only {0,1,7})
    {
        float2 o2;
        o2.x = fmaxf(d[0][0], 0.f); o2.y = fmaxf(d[1][0], 0.f);
        *(float2*)&xls[3][s][obase] = o2;                // y3@9
        o2.x = fmaxf(d[0][1], 0.f); o2.y = fmaxf(d[1][1], 0.f);
        *(float2*)&xls[8][s][obase] = o2;                // y3@11
    }
    __syncthreads();

    // ---- stage 4: l1 conv2 (D=2) at t=11; y3 slots {3,8}
    float f[2];
    {
        const float2 bv = *(const float2*)(tb2 + 64 + obase);
        f[0] = bv.x; f[1] = bv.y;
    }
#pragma unroll 2
    for (int ig = 0; ig < 16; ++ig) {
        const float4 g0 = *(const float4*)&xls[3][s][ig * 4];   // y3@9
        const float4 g1 = *(const float4*)&xls[8][s][ig * 4];   // y3@11
#pragma unroll
        for (int oo = 0; oo < 2; ++oo) {
            const float4 wA = Wf4[((48 + ig) * 64 + obase + oo) * 2 + 0];
            const float4 wB = Wf4[((48 + ig) * 64 + obase + oo) * 2 + 1];
            float t0 = f[oo];
            t0 = fmaf(wA.x, g0.x, t0);  t0 = fmaf(wA.y, g1.x, t0);
            t0 = fmaf(wA.z, g0.y, t0);  t0 = fmaf(wA.w, g1.y, t0);
            t0 = fmaf(wB.x, g0.z, t0);  t0 = fmaf(wB.y, g1.z, t0);
            t0 = fmaf(wB.z, g0.w, t0);  t0 = fmaf(wB.w, g1.w, t0);
            f[oo] = t0;
        }
    }
    // ht = relu(relu(f) + x2@11)
    float ht[2];
    {
        const float2 xr = *(const float2*)&xls[7][s][obase];
        ht[0] = fmaxf(fmaxf(f[0], 0.f) + xr.x, 0.f);
        ht[1] = fmaxf(fmaxf(f[1], 0.f) + xr.y, 0.f);
    }

    // ---- epilogue: gate (cross-hg shfl strides 8..32 + cross-wave LDS)
    float* pbuf = &xls[2][0][0];                         // slot 2 free now
    {
        const float2 wg2 = *(const float2*)(wgate + obase);
        float p = ht[0] * wg2.x + ht[1] * wg2.y;
        p += __shfl_xor(p, 8); p += __shfl_xor(p, 16); p += __shfl_xor(p, 32);
        if (hg == 0) pbuf[wfl * 8 + s] = p;
    }
    __syncthreads();
    float ptot = 0.f;
#pragma unroll
    for (int w4i = 0; w4i < 4; ++w4i) ptot += pbuf[w4i * 8 + s];
    const float g = 1.f / (1.f + expf(-(ptot + bgate[0])));
    float fo[2];
    {
        const float2 hs = *(const float2*)&xls[6][s][obase];   // x1@11
        fo[0] = g * ht[0] + (1.f - g) * hs.x;
        fo[1] = g * ht[1] + (1.f - g) * hs.y;
    }
    float po[12];
#pragma unroll
    for (int h2 = 0; h2 < 12; ++h2) po[h2] = 0.f;
#pragma unroll
    for (int oo = 0; oo < 2; ++oo) {
        const float* wr = wout + (obase + oo) * 12;
        const float4 w0 = *(const float4*)(wr);
        const float4 w1 = *(const float4*)(wr + 4);
        const float4 w2 = *(const float4*)(wr + 8);
        po[0] = fmaf(fo[oo], w0.x, po[0]);  po[1] = fmaf(fo[oo], w0.y, po[1]);
        po[2] = fmaf(fo[oo], w0.z, po[2]);  po[3] = fmaf(fo[oo], w0.w, po[3]);
        po[4] = fmaf(fo[oo], w1.x, po[4]);  po[5] = fmaf(fo[oo], w1.y, po[5]);
        po[6] = fmaf(fo[oo], w1.z, po[6]);  po[7] = fmaf(fo[oo], w1.w, po[7]);
        po[8] = fmaf(fo[oo], w2.x, po[8]);  po[9] = fmaf(fo[oo], w2.y, po[9]);
        po[10] = fmaf(fo[oo], w2.z, po[10]); po[11] = fmaf(fo[oo], w2.w, po[11]);
    }
#pragma unroll
    for (int h2 = 0; h2 < 12; ++h2) {
        po[h2] += __shfl_xor(po[h2], 8);
        po[h2] += __shfl_xor(po[h2], 16);
        po[h2] += __shfl_xor(po[h2], 32);
    }
    float* pobuf = &xls[4][0][0];                        // slots 4-5 free (1088 f)
    if (hg == 0) {
#pragma unroll
        for (int h2 = 0; h2 < 12; ++h2)
            pobuf[(wfl * 12 + h2) * 8 + s] = po[h2];
    }
    __syncthreads();
    if (tid < 96) {
        const int h2 = tid >> 3, sq = tid & 7;
        float r = bout[h2];
#pragma unroll
        for (int w4i = 0; w4i < 4; ++w4i)
            r += pobuf[(w4i * 12 + h2) * 8 + sq];
        outp[h2 * 8000 + bI * 2000 + n0 + sq] = r;
    }
}

extern "C" void kernel_launch(void* const* d_in, const int* in_sizes, int n_in,
                              void* d_out, int out_size, void* d_ws, size_t ws_size,
                              hipStream_t stream) {
    const float* inputs     = (const float*)d_in[0];
    const float* node_feas  = (const float*)d_in[1];
    const int*   node_index = (const int*)  d_in[2];
    const float* w_fc3 = (const float*)d_in[3];
    const float* b_fc3 = (const float*)d_in[4];
    const float* w_fc4 = (const float*)d_in[5];
    const float* b_fc4 = (const float*)d_in[6];
    const float* w_fc5 = (const float*)d_in[7];
    const float* b_fc5 = (const float*)d_in[8];
    const float* w_nhp = (const float*)d_in[9];
    const float* b_nhp = (const float*)d_in[10];
    const float* w_q   = (const float*)d_in[11];
    const float* w_k   = (const float*)d_in[12];
    const float* w_in  = (const float*)d_in[13];
    const float* b_in  = (const float*)d_in[14];
    const float* sws   = (const float*)d_in[15];
    const float* sbs   = (const float*)d_in[16];
    const float* swn   = (const float*)d_in[17];
    const float* sbn   = (const float*)d_in[18];
    const float* tw1   = (const float*)d_in[19];
    const float* tb1   = (const float*)d_in[20];
    const float* tw2   = (const float*)d_in[21];
    const float* tb2   = (const float*)d_in[22];
    const float* wgate = (const float*)d_in[23];
    const float* bgate = (const float*)d_in[24];
    const float* wout  = (const float*)d_in[25];
    const float* bout  = (const float*)d_in[26];

    float* out  = (float*)d_out;           // (12,4,2000)        96000
    float* mid  = out + 96000;             // (4,12,2000,64)     6144000
    float* wadj = mid + 6144000;           // (2000,32)          64000

    float*  q     = (float*)d_ws;          // 128000
    float*  ek    = q     + 128000;        // 128000
    float*  nh2   = ek    + 128000;        // 128000 (includes b_nhp + b_in)
    float*  base1 = nh2   + 128000;        // 128000
    float*  xT    = base1 + 128000;        // 96000   [n][bt]
    float2* xa    = (float2*)(xT + 96000); // 96000 float2 {x, ax}
    float*  vecs  = xT + 96000 + 192000;   // 128 {s1v, n1v}
    float2* W2    = (float2*)(vecs + 128); // 16384 float2 (TCN weights [c][ig][o][ii])
    float4* wsg   = (float4*)(vecs + 128 + 32768);  // 4096 float4 (SAGE packed)

    k_embed<<<500, 256, 0, stream>>>(node_feas, inputs, w_fc3, b_fc3, w_fc4, b_fc4,
                                     w_fc5, b_fc5, w_q, w_k, w_nhp, b_nhp, b_in,
                                     tw1, tw2, sws, swn, W2, wsg,
                                     q, ek, nh2, xT);
    k_front<<<501, 256, 0, stream>>>(q, ek, xT, nh2, node_index,
                                     sws, sbs, swn, sbn, w_in, wsg,
                                     wadj, xa, base1, vecs);
    k_sage2<<<2000, 512, 0, stream>>>(base1, xa, vecs, node_index, wadj,
                                      wsg + 2048, sbs, sbn, mid);
    k_tcn<<<1000, 256, 0, stream>>>(mid, W2, tb1, tb2,
                                    wgate, bgate, wout, bout, out);
}

// Round 16
// 112.648 us; speedup vs baseline: 1.5483x; 1.5483x over previous
//
#include <hip/hip_runtime.h>
#include <math.h>

// Sizes: N=2000, M=32, H=64, EMB=32, F=32, T=12, B=4, HOR=12, K=2, DILS=(1,2)

// ---------------- K1: node MLP -> q, ek, nh2; also xT, TCN W2 pack, SAGE wpack ----
__global__ __launch_bounds__(256) void k_embed(
    const float* __restrict__ nf, const float* __restrict__ inputs,
    const float* __restrict__ w3, const float* __restrict__ b3,
    const float* __restrict__ w4, const float* __restrict__ b4,
    const float* __restrict__ w5, const float* __restrict__ b5,
    const float* __restrict__ wq, const float* __restrict__ wk,
    const float* __restrict__ wn, const float* __restrict__ bn,
    const float* __restrict__ b_in,
    const float* __restrict__ tw1, const float* __restrict__ tw2,
    const float* __restrict__ sws, const float* __restrict__ swn,
    float2* __restrict__ W2, float4* __restrict__ wsg,
    float* __restrict__ qo, float* __restrict__ eko, float* __restrict__ nho,
    float* __restrict__ xT)
{
    const int tid = threadIdx.x;
    if (tid < 192) {                                   // xT transpose: 500*192 = 96000
        const int id = blockIdx.x * 192 + tid;
        const int t = id / 8000, rem = id % 8000;
        const int b = rem / 2000, n2 = rem % 2000;
        xT[n2 * 48 + b * 12 + t] = inputs[id];
    }
    if (blockIdx.x < 64) {            // TCN weights -> [c][ig][o][ii]{k0,k1}, 16384 f2
        const int id = blockIdx.x * 256 + tid;
        const int c = id >> 12, r = id & 4095;
        const int ig = r >> 8, o = (r >> 2) & 63, ii = r & 3;
        const float* src = (c == 0) ? tw1 : (c == 1) ? tw2
                         : (c == 2) ? tw1 + 8192 : tw2 + 8192;
        const int i = ig * 4 + ii;
        W2[id] = make_float2(src[o * 128 + i * 2], src[o * 128 + i * 2 + 1]);
    } else if (blockIdx.x < 80) {                      // SAGE weights -> [l][k2][h] float4
        const int id = (blockIdx.x - 64) * 256 + tid;  // 0..4095
        const int l = id >> 11, rr = id & 2047;
        const int k2 = rr >> 6, h = rr & 63;
        const float* S = sws + l * 4096;
        const float* Nn = swn + l * 4096;
        wsg[id] = make_float4(S[(2 * k2) * 64 + h],     Nn[(2 * k2) * 64 + h],
                              S[(2 * k2 + 1) * 64 + h], Nn[(2 * k2 + 1) * 64 + h]);
    }
    const int lane = tid & 63;
    const int n = blockIdx.x * 4 + (tid >> 6);

    float nfv = 0.f;
    if (lane < 32) nfv = nf[n * 32 + lane];

    float e1 = b3[lane];
#pragma unroll
    for (int f = 0; f < 32; ++f)
        e1 = fmaf(__shfl(nfv, f), w3[f * 64 + lane], e1);
    e1 = fmaxf(e1, 0.f);

    float e2 = b4[lane];
#pragma unroll
    for (int f = 0; f < 64; ++f)
        e2 = fmaf(__shfl(e1, f), w4[f * 64 + lane], e2);
    e2 = fmaxf(e2, 0.f);

    const int c = lane & 31;
    float ev = b5[c];
#pragma unroll
    for (int f = 0; f < 64; ++f)
        ev = fmaf(__shfl(e2, f), w5[f * 32 + c], ev);

    float qv = 0.f, ekv = 0.f, nhv = bn[lane] + b_in[lane];
#pragma unroll
    for (int f = 0; f < 32; ++f) {
        float e = __shfl(ev, f);
        qv  = fmaf(e, wq[f * 64 + lane], qv);
        ekv = fmaf(e, wk[f * 64 + lane], ekv);
        nhv = fmaf(e, wn[f * 64 + lane], nhv);
    }
    qo [n * 64 + lane] = qv;
    eko[n * 64 + lane] = ekv;
    nho[n * 64 + lane] = nhv;
}

// ---------------- K2: fused scores+softmax -> wadj; ax -> xa; base1 (+vecs) ----
__global__ __launch_bounds__(256) void k_front(
    const float* __restrict__ q, const float* __restrict__ ek,
    const float* __restrict__ xT, const float* __restrict__ nh2,
    const int* __restrict__ nidx,
    const float* __restrict__ sws, const float* __restrict__ sbs,
    const float* __restrict__ swn, const float* __restrict__ sbn,
    const float* __restrict__ w_in, const float4* __restrict__ wsg,
    float* __restrict__ wadj, float2* __restrict__ xa,
    float* __restrict__ base1, float* __restrict__ vecs)
{
    const int tid = threadIdx.x;
    const int lane = tid & 63, wave = tid >> 6;
    if (blockIdx.x == 500) {
        if (wave == 0) {
            const float wv = w_in[lane];
            float s1 = 0.f, n1 = 0.f;
#pragma unroll
            for (int k = 0; k < 64; ++k) {
                const float wkk = __shfl(wv, k);
                s1 = fmaf(wkk, sws[k * 64 + lane], s1);
                n1 = fmaf(wkk, swn[k * 64 + lane], n1);
            }
            vecs[lane] = s1; vecs[64 + lane] = n1;
        }
        return;
    }
    __shared__ __align__(16) float2 pair[4][64];
    const int n = blockIdx.x * 4 + wave;

    int j = 0;
    if (lane < 32) j = nidx[n * 32 + lane];
    float w;
    {
        const float4* qr = (const float4*)(q + n * 64);
        const float4* er = (const float4*)(ek + j * 64);
        float s = 0.f;
#pragma unroll
        for (int u = 0; u < 16; ++u) {
            const float4 a = qr[u], b = er[u];
            s = fmaf(a.x, b.x, s); s = fmaf(a.y, b.y, s);
            s = fmaf(a.z, b.z, s); s = fmaf(a.w, b.w, s);
        }
        s *= 0.125f;
        float mx = s;
#pragma unroll
        for (int d = 16; d >= 1; d >>= 1) mx = fmaxf(mx, __shfl_xor(mx, d));
        const float ex = expf(s - mx);
        float sum = ex;
#pragma unroll
        for (int d = 16; d >= 1; d >>= 1) sum += __shfl_xor(sum, d);
        w = ex / sum;
        if (lane < 32) wadj[n * 32 + lane] = w;
    }
    float ax = 0.f, anh = 0.f;
    const bool act = lane < 48;
#pragma unroll 8
    for (int m = 0; m < 32; ++m) {
        const int jm = __shfl(j, m);
        const float wm = __shfl(w, m);
        const float xv = act ? xT[jm * 48 + lane] : 0.f;
        ax  = fmaf(wm, xv, ax);
        anh = fmaf(wm, nh2[jm * 64 + lane], anh);
    }
    if (act) xa[n * 48 + lane] = make_float2(xT[n * 48 + lane], ax);
    pair[wave][lane] = make_float2(nh2[n * 64 + lane], anh);
    __syncthreads();

    float acc = sbs[lane] + sbn[lane];
    const float2* pw = pair[wave];
#pragma unroll
    for (int k2 = 0; k2 < 32; ++k2) {
        const float4 wv = wsg[k2 * 64 + lane];
        const float4 sv = *(const float4*)(pw + k2 * 2);
        acc = fmaf(sv.x, wv.x, acc); acc = fmaf(sv.y, wv.y, acc);
        acc = fmaf(sv.z, wv.z, acc); acc = fmaf(sv.w, wv.w, acc);
    }
    base1[n * 64 + lane] = acc;
}

// ---------------- K3: fused SAGE layer 2 (recompute h1 from scalars) -> mid ----------
__global__ __launch_bounds__(512, 8) void k_sage2(
    const float* __restrict__ base1, const float2* __restrict__ xa,
    const float* __restrict__ vecs,
    const int* __restrict__ nidx, const float* __restrict__ wadj,
    const float4* __restrict__ wsg2,
    const float* __restrict__ sbs, const float* __restrict__ sbn,
    float* __restrict__ mid)
{
    __shared__ __align__(16) float2 svp[48][64];        // {h1self, agg}, 24 KB
    const int tid = threadIdx.x, lane = tid & 63;
    const int wave = __builtin_amdgcn_readfirstlane(tid >> 6);
    const int n = blockIdx.x;
    const int bt0 = wave * 6;

    const float s1 = vecs[lane], n1 = vecs[64 + lane];
    const float bs = base1[n * 64 + lane];

    float agg[6] = {0.f, 0.f, 0.f, 0.f, 0.f, 0.f};
#pragma unroll 8
    for (int m = 0; m < 32; ++m) {
        const int j = nidx[n * 32 + m];                 // block-uniform -> s_load
        const float w = wadj[n * 32 + m];               // block-uniform -> s_load
        const float bj = base1[j * 64 + lane];
        const float4* xr = (const float4*)(xa + j * 48 + bt0);
        const float4 p0 = xr[0], p1 = xr[1], p2 = xr[2];
        float t;
        t = fmaf(p0.x, s1, fmaf(p0.y, n1, bj)); agg[0] = fmaf(w, fmaxf(t, 0.f), agg[0]);
        t = fmaf(p0.z, s1, fmaf(p0.w, n1, bj)); agg[1] = fmaf(w, fmaxf(t, 0.f), agg[1]);
        t = fmaf(p1.x, s1, fmaf(p1.y, n1, bj)); agg[2] = fmaf(w, fmaxf(t, 0.f), agg[2]);
        t = fmaf(p1.z, s1, fmaf(p1.w, n1, bj)); agg[3] = fmaf(w, fmaxf(t, 0.f), agg[3]);
        t = fmaf(p2.x, s1, fmaf(p2.y, n1, bj)); agg[4] = fmaf(w, fmaxf(t, 0.f), agg[4]);
        t = fmaf(p2.z, s1, fmaf(p2.w, n1, bj)); agg[5] = fmaf(w, fmaxf(t, 0.f), agg[5]);
    }
    {
        const float4* xs = (const float4*)(xa + n * 48 + bt0);
        const float4 q0 = xs[0], q1 = xs[1], q2 = xs[2];
        svp[bt0 + 0][lane] = make_float2(fmaxf(fmaf(q0.x, s1, fmaf(q0.y, n1, bs)), 0.f), agg[0]);
        svp[bt0 + 1][lane] = make_float2(fmaxf(fmaf(q0.z, s1, fmaf(q0.w, n1, bs)), 0.f), agg[1]);
        svp[bt0 + 2][lane] = make_float2(fmaxf(fmaf(q1.x, s1, fmaf(q1.y, n1, bs)), 0.f), agg[2]);
        svp[bt0 + 3][lane] = make_float2(fmaxf(fmaf(q1.z, s1, fmaf(q1.w, n1, bs)), 0.f), agg[3]);
        svp[bt0 + 4][lane] = make_float2(fmaxf(fmaf(q2.x, s1, fmaf(q2.y, n1, bs)), 0.f), agg[4]);
        svp[bt0 + 5][lane] = make_float2(fmaxf(fmaf(q2.z, s1, fmaf(q2.w, n1, bs)), 0.f), agg[5]);
    }
    const float b2 = sbs[64 + lane] + sbn[64 + lane];
    float acc[6] = {b2, b2, b2, b2, b2, b2};
    const float4* wp = wsg2 + lane;
    const float2* s0 = svp[bt0];
#pragma unroll
    for (int k2 = 0; k2 < 32; ++k2) {
        const float4 w4 = wp[k2 * 64];
        const float4 v0 = *(const float4*)(s0 + 0 * 64 + k2 * 2);
        const float4 v1 = *(const float4*)(s0 + 1 * 64 + k2 * 2);
        const float4 v2 = *(const float4*)(s0 + 2 * 64 + k2 * 2);
        const float4 v3 = *(const float4*)(s0 + 3 * 64 + k2 * 2);
        const float4 v4 = *(const float4*)(s0 + 4 * 64 + k2 * 2);
        const float4 v5 = *(const float4*)(s0 + 5 * 64 + k2 * 2);
        acc[0] = fmaf(v0.x, w4.x, fmaf(v0.y, w4.y, fmaf(v0.z, w4.z, fmaf(v0.w, w4.w, acc[0]))));
        acc[1] = fmaf(v1.x, w4.x, fmaf(v1.y, w4.y, fmaf(v1.z, w4.z, fmaf(v1.w, w4.w, acc[1]))));
        acc[2] = fmaf(v2.x, w4.x, fmaf(v2.y, w4.y, fmaf(v2.z, w4.z, fmaf(v2.w, w4.w, acc[2]))));
        acc[3] = fmaf(v3.x, w4.x, fmaf(v3.y, w4.y, fmaf(v3.z, w4.z, fmaf(v3.w, w4.w, acc[3]))));
        acc[4] = fmaf(v4.x, w4.x, fmaf(v4.y, w4.y, fmaf(v4.z, w4.z, fmaf(v4.w, w4.w, acc[4]))));
        acc[5] = fmaf(v5.x, w4.x, fmaf(v5.y, w4.y, fmaf(v5.z, w4.z, fmaf(v5.w, w4.w, acc[5]))));
    }
#pragma unroll
    for (int r = 0; r < 6; ++r)
        mid[((bt0 + r) * 2000 + n) * 64 + lane] = fmaxf(acc[r], 0.f);
}

// ---------------- K4: TCN seq-parallel GEMM, 256 thr / 4 waves / 8 seqs / 2 ch/lane ----
// block = 8 seqs; lane = (hg,s): s = seq (8), hg -> 2-ch subtile (8 groups);
// wave covers 16 out-ch (obase = wfl*16 + hg*2). 1000 blocks, LDS 19.1 KB.
// __launch_bounds__(256,4): 128-VGPR budget -> no spill (r15's (256,8)=64 cap
// forced 32 VGPR + 173 MB scratch; that was the whole regression). Occupancy
// then LDS-limited at 8 blocks/CU = 32 waves/CU.
__global__ __launch_bounds__(256, 4) void k_tcn(
    const float* __restrict__ mid, const float2* __restrict__ W2,
    const float* __restrict__ tb1, const float* __restrict__ tb2,
    const float* __restrict__ wgate, const float* __restrict__ bgate,
    const float* __restrict__ wout, const float* __restrict__ bout,
    float* __restrict__ outp)
{
    __shared__ __align__(16) float xls[9][8][68];        // 19.1 KB
    const int tid = threadIdx.x, lane = tid & 63;
    const int wfl = __builtin_amdgcn_readfirstlane(tid >> 6);   // 0..3
    const int hg = (lane >> 3) & 7;
    const int s = lane & 7;
    const int bI = blockIdx.x / 250;                     // 250 blocks per b (2000/8)
    const int n0 = (blockIdx.x - bI * 250) * 8;
    const long base = ((long)(bI * 12) * 2000 + n0) * 64;
    const int obase = wfl * 16 + hg * 2;                 // 2 ch per lane
    const float4* __restrict__ Wf4 = (const float4*)W2;  // [(c*16+ig)*64+o]*2 {+0,+1}

    // ---- stage 0: stage x1[t=5..11] -> slots 0..6, layout [slot][s][ch]
    for (int e = tid; e < 896; e += 256) {
        const int u = e >> 7, rem = e & 127;
        const int ss = rem >> 4, qq = rem & 15;
        const float4 v = *(const float4*)(mid + base + (5 + u) * 128000L + ss * 64 + qq * 4);
        *(float4*)&xls[u][ss][qq * 4] = v;
    }
    __syncthreads();

    // ---- stage 1: l0 conv1 (D=1): y1[t=6..11]
    float y[2][6];
    {
        const float2 bv = *(const float2*)(tb1 + obase);
#pragma unroll
        for (int j = 0; j < 6; ++j) { y[0][j] = bv.x; y[1][j] = bv.y; }
    }
#pragma unroll 2
    for (int ig = 0; ig < 16; ++ig) {
        float4 xv[7];
#pragma unroll
        for (int u = 0; u < 7; ++u)
            xv[u] = *(const float4*)&xls[u][s][ig * 4];
#pragma unroll
        for (int oo = 0; oo < 2; ++oo) {
            const float4 wA = Wf4[(ig * 64 + obase + oo) * 2 + 0];
            const float4 wB = Wf4[(ig * 64 + obase + oo) * 2 + 1];
#pragma unroll
            for (int j = 0; j < 6; ++j) {
                float acc = y[oo][j];
                acc = fmaf(wA.x, xv[j].x, acc); acc = fmaf(wA.y, xv[j+1].x, acc);
                acc = fmaf(wA.z, xv[j].y, acc); acc = fmaf(wA.w, xv[j+1].y, acc);
                acc = fmaf(wB.x, xv[j].z, acc); acc = fmaf(wB.y, xv[j+1].z, acc);
                acc = fmaf(wB.z, xv[j].w, acc); acc = fmaf(wB.w, xv[j+1].w, acc);
                y[oo][j] = acc;
            }
        }
    }
    __syncthreads();                                     // all stage-1 reads done
    // y1 -> slots {0,1,7,3,8,5} (x1 slots 2,4,6 = residuals preserved)
    {
        const int S1OUT[6] = {0, 1, 7, 3, 8, 5};
#pragma unroll
        for (int j = 0; j < 6; ++j) {
            float2 o2;
            o2.x = fmaxf(y[0][j], 0.f); o2.y = fmaxf(y[1][j], 0.f);
            *(float2*)&xls[S1OUT[j]][s][obase] = o2;
        }
    }
    __syncthreads();

    // ---- stage 2: l0 conv2 (D=1) at t=7,9,11
    float a[2][3];
    {
        const float2 bv = *(const float2*)(tb2 + obase);
#pragma unroll
        for (int v = 0; v < 3; ++v) { a[0][v] = bv.x; a[1][v] = bv.y; }
    }
#pragma unroll 2
    for (int ig = 0; ig < 16; ++ig) {
        const float4 y0 = *(const float4*)&xls[0][s][ig * 4];   // y1@6
        const float4 y1v = *(const float4*)&xls[1][s][ig * 4];  // y1@7
        const float4 y2 = *(const float4*)&xls[7][s][ig * 4];   // y1@8
        const float4 y3v = *(const float4*)&xls[3][s][ig * 4];  // y1@9
        const float4 y4 = *(const float4*)&xls[8][s][ig * 4];   // y1@10
        const float4 y5 = *(const float4*)&xls[5][s][ig * 4];   // y1@11
#pragma unroll
        for (int oo = 0; oo < 2; ++oo) {
            const float4 wA = Wf4[((16 + ig) * 64 + obase + oo) * 2 + 0];
            const float4 wB = Wf4[((16 + ig) * 64 + obase + oo) * 2 + 1];
            float t0 = a[oo][0], t1 = a[oo][1], t2 = a[oo][2];
            t0 = fmaf(wA.x, y0.x, t0);  t0 = fmaf(wA.y, y1v.x, t0);
            t0 = fmaf(wA.z, y0.y, t0);  t0 = fmaf(wA.w, y1v.y, t0);
            t0 = fmaf(wB.x, y0.z, t0);  t0 = fmaf(wB.y, y1v.z, t0);
            t0 = fmaf(wB.z, y0.w, t0);  t0 = fmaf(wB.w, y1v.w, t0);
            t1 = fmaf(wA.x, y2.x, t1);  t1 = fmaf(wA.y, y3v.x, t1);
            t1 = fmaf(wA.z, y2.y, t1);  t1 = fmaf(wA.w, y3v.y, t1);
            t1 = fmaf(wB.x, y2.z, t1);  t1 = fmaf(wB.y, y3v.z, t1);
            t1 = fmaf(wB.z, y2.w, t1);  t1 = fmaf(wB.w, y3v.w, t1);
            t2 = fmaf(wA.x, y4.x, t2);  t2 = fmaf(wA.y, y5.x, t2);
            t2 = fmaf(wA.z, y4.y, t2);  t2 = fmaf(wA.w, y5.y, t2);
            t2 = fmaf(wB.x, y4.z, t2);  t2 = fmaf(wB.y, y5.z, t2);
            t2 = fmaf(wB.z, y4.w, t2);  t2 = fmaf(wB.w, y5.w, t2);
            a[oo][0] = t0; a[oo][1] = t1; a[oo][2] = t2;
        }
    }
    __syncthreads();                                     // stage-2 reads done
    // x2[t] = relu(relu(a) + x1[t]) -> slots {0,1,7}; residuals slots {2,4,6}
    {
        const int RIN[3] = {2, 4, 6}, ROUT[3] = {0, 1, 7};
#pragma unroll
        for (int v = 0; v < 3; ++v) {
            const float2 xr = *(const float2*)&xls[RIN[v]][s][obase];
            float2 o2;
            o2.x = fmaxf(fmaxf(a[0][v], 0.f) + xr.x, 0.f);
            o2.y = fmaxf(fmaxf(a[1][v], 0.f) + xr.y, 0.f);
            *(float2*)&xls[ROUT[v]][s][obase] = o2;
        }
    }
    __syncthreads();

    // ---- stage 3: l1 conv1 (D=2) at t=9,11; x2 slots {0,1,7}
    float d[2][2];
    {
        const float2 bv = *(const float2*)(tb1 + 64 + obase);
        d[0][0] = bv.x; d[0][1] = bv.x; d[1][0] = bv.y; d[1][1] = bv.y;
    }
#pragma unroll 2
    for (int ig = 0; ig < 16; ++ig) {
        const float4 x0 = *(const float4*)&xls[0][s][ig * 4];   // x2@7
        const float4 x1 = *(const float4*)&xls[1][s][ig * 4];   // x2@9
        const float4 x2 = *(const float4*)&xls[7][s][ig * 4];   // x2@11
#pragma unroll
        for (int oo = 0; oo < 2; ++oo) {
            const float4 wA = Wf4[((32 + ig) * 64 + obase + oo) * 2 + 0];
            const float4 wB = Wf4[((32 + ig) * 64 + obase + oo) * 2 + 1];
            float t0 = d[oo][0], t1 = d[oo][1];
            t0 = fmaf(wA.x, x0.x, t0);  t0 = fmaf(wA.y, x1.x, t0);
            t0 = fmaf(wA.z, x0.y, t0);  t0 = fmaf(wA.w, x1.y, t0);
            t0 = fmaf(wB.x, x0.z, t0);  t0 = fmaf(wB.y, x1.z, t0);
            t0 = fmaf(wB.z, x0.w, t0);  t0 = fmaf(wB.w, x1.w, t0);
            t1 = fmaf(wA.x, x1.x, t1);  t1 = fmaf(wA.y, x2.x, t1);
            t1 = fmaf(wA.z, x1.y, t1);  t1 = fmaf(wA.w, x2.y, t1);
            t1 = fmaf(wB.x, x1.z, t1);  t1 = fmaf(wB.y, x2.z, t1);
            t1 = fmaf(wB.z, x1.w, t1);  t1 = fmaf(wB.w, x2.w, t1);
            d[oo][0] = t0; d[oo][1] = t1;
        }
    }
    // y3 -> slots {3,8} (y1 dead; stage-3 reads only {0,1,7})
    {
        float2 o2;
        o2.x = fmaxf(d[0][0], 0.f); o2.y = fmaxf(d[1][0], 0.f);
        *(float2*)&xls[3][s][obase] = o2;                // y3@9
        o2.x = fmaxf(d[0][1], 0.f); o2.y = fmaxf(d[1][1], 0.f);
        *(float2*)&xls[8][s][obase] = o2;                // y3@11
    }
    __syncthreads();

    // ---- stage 4: l1 conv2 (D=2) at t=11; y3 slots {3,8}
    float f[2];
    {
        const float2 bv = *(const float2*)(tb2 + 64 + obase);
        f[0] = bv.x; f[1] = bv.y;
    }
#pragma unroll 2
    for (int ig = 0; ig < 16; ++ig) {
        const float4 g0 = *(const float4*)&xls[3][s][ig * 4];   // y3@9
        const float4 g1 = *(const float4*)&xls[8][s][ig * 4];   // y3@11
#pragma unroll
        for (int oo = 0; oo < 2; ++oo) {
            const float4 wA = Wf4[((48 + ig) * 64 + obase + oo) * 2 + 0];
            const float4 wB = Wf4[((48 + ig) * 64 + obase + oo) * 2 + 1];
            float t0 = f[oo];
            t0 = fmaf(wA.x, g0.x, t0);  t0 = fmaf(wA.y, g1.x, t0);
            t0 = fmaf(wA.z, g0.y, t0);  t0 = fmaf(wA.w, g1.y, t0);
            t0 = fmaf(wB.x, g0.z, t0);  t0 = fmaf(wB.y, g1.z, t0);
            t0 = fmaf(wB.z, g0.w, t0);  t0 = fmaf(wB.w, g1.w, t0);
            f[oo] = t0;
        }
    }
    // ht = relu(relu(f) + x2@11)
    float ht[2];
    {
        const float2 xr = *(const float2*)&xls[7][s][obase];
        ht[0] = fmaxf(fmaxf(f[0], 0.f) + xr.x, 0.f);
        ht[1] = fmaxf(fmaxf(f[1], 0.f) + xr.y, 0.f);
    }

    // ---- epilogue: gate (cross-hg shfl strides 8..32 + cross-wave LDS)
    float* pbuf = &xls[2][0][0];                         // slot 2 free now
    {
        const float2 wg2 = *(const float2*)(wgate + obase);
        float p = ht[0] * wg2.x + ht[1] * wg2.y;
        p += __shfl_xor(p, 8); p += __shfl_xor(p, 16); p += __shfl_xor(p, 32);
        if (hg == 0) pbuf[wfl * 8 + s] = p;
    }
    __syncthreads();
    float ptot = 0.f;
#pragma unroll
    for (int w4i = 0; w4i < 4; ++w4i) ptot += pbuf[w4i * 8 + s];
    const float g = 1.f / (1.f + expf(-(ptot + bgate[0])));
    float fo[2];
    {
        const float2 hs = *(const float2*)&xls[6][s][obase];   // x1@11
        fo[0] = g * ht[0] + (1.f - g) * hs.x;
        fo[1] = g * ht[1] + (1.f - g) * hs.y;
    }
    float po[12];
#pragma unroll
    for (int h2 = 0; h2 < 12; ++h2) po[h2] = 0.f;
#pragma unroll
    for (int oo = 0; oo < 2; ++oo) {
        const float* wr = wout + (obase + oo) * 12;
        const float4 w0 = *(const float4*)(wr);
        const float4 w1 = *(const float4*)(wr + 4);
        const float4 w2 = *(const float4*)(wr + 8);
        po[0] = fmaf(fo[oo], w0.x, po[0]);  po[1] = fmaf(fo[oo], w0.y, po[1]);
        po[2] = fmaf(fo[oo], w0.z, po[2]);  po[3] = fmaf(fo[oo], w0.w, po[3]);
        po[4] = fmaf(fo[oo], w1.x, po[4]);  po[5] = fmaf(fo[oo], w1.y, po[5]);
        po[6] = fmaf(fo[oo], w1.z, po[6]);  po[7] = fmaf(fo[oo], w1.w, po[7]);
        po[8] = fmaf(fo[oo], w2.x, po[8]);  po[9] = fmaf(fo[oo], w2.y, po[9]);
        po[10] = fmaf(fo[oo], w2.z, po[10]); po[11] = fmaf(fo[oo], w2.w, po[11]);
    }
#pragma unroll
    for (int h2 = 0; h2 < 12; ++h2) {
        po[h2] += __shfl_xor(po[h2], 8);
        po[h2] += __shfl_xor(po[h2], 16);
        po[h2] += __shfl_xor(po[h2], 32);
    }
    float* pobuf = &xls[4][0][0];                        // slots 4-5 free (1088 f)
    if (hg == 0) {
#pragma unroll
        for (int h2 = 0; h2 < 12; ++h2)
            pobuf[(wfl * 12 + h2) * 8 + s] = po[h2];
    }
    __syncthreads();
    if (tid < 96) {
        const int h2 = tid >> 3, sq = tid & 7;
        float r = bout[h2];
#pragma unroll
        for (int w4i = 0; w4i < 4; ++w4i)
            r += pobuf[(w4i * 12 + h2) * 8 + sq];
        outp[h2 * 8000 + bI * 2000 + n0 + sq] = r;
    }
}

extern "C" void kernel_launch(void* const* d_in, const int* in_sizes, int n_in,
                              void* d_out, int out_size, void* d_ws, size_t ws_size,
                              hipStream_t stream) {
    const float* inputs     = (const float*)d_in[0];
    const float* node_feas  = (const float*)d_in[1];
    const int*   node_index = (const int*)  d_in[2];
    const float* w_fc3 = (const float*)d_in[3];
    const float* b_fc3 = (const float*)d_in[4];
    const float* w_fc4 = (const float*)d_in[5];
    const float* b_fc4 = (const float*)d_in[6];
    const float* w_fc5 = (const float*)d_in[7];
    const float* b_fc5 = (const float*)d_in[8];
    const float* w_nhp = (const float*)d_in[9];
    const float* b_nhp = (const float*)d_in[10];
    const float* w_q   = (const float*)d_in[11];
    const float* w_k   = (const float*)d_in[12];
    const float* w_in  = (const float*)d_in[13];
    const float* b_in  = (const float*)d_in[14];
    const float* sws   = (const float*)d_in[15];
    const float* sbs   = (const float*)d_in[16];
    const float* swn   = (const float*)d_in[17];
    const float* sbn   = (const float*)d_in[18];
    const float* tw1   = (const float*)d_in[19];
    const float* tb1   = (const float*)d_in[20];
    const float* tw2   = (const float*)d_in[21];
    const float* tb2   = (const float*)d_in[22];
    const float* wgate = (const float*)d_in[23];
    const float* bgate = (const float*)d_in[24];
    const float* wout  = (const float*)d_in[25];
    const float* bout  = (const float*)d_in[26];

    float* out  = (float*)d_out;           // (12,4,2000)        96000
    float* mid  = out + 96000;             // (4,12,2000,64)     6144000
    float* wadj = mid + 6144000;           // (2000,32)          64000

    float*  q     = (float*)d_ws;          // 128000
    float*  ek    = q     + 128000;        // 128000
    float*  nh2   = ek    + 128000;        // 128000 (includes b_nhp + b_in)
    float*  base1 = nh2   + 128000;        // 128000
    float*  xT    = base1 + 128000;        // 96000   [n][bt]
    float2* xa    = (float2*)(xT + 96000); // 96000 float2 {x, ax}
    float*  vecs  = xT + 96000 + 192000;   // 128 {s1v, n1v}
    float2* W2    = (float2*)(vecs + 128); // 16384 float2 (TCN weights [c][ig][o][ii])
    float4* wsg   = (float4*)(vecs + 128 + 32768);  // 4096 float4 (SAGE packed)

    k_embed<<<500, 256, 0, stream>>>(node_feas, inputs, w_fc3, b_fc3, w_fc4, b_fc4,
                                     w_fc5, b_fc5, w_q, w_k, w_nhp, b_nhp, b_in,
                                     tw1, tw2, sws, swn, W2, wsg,
                                     q, ek, nh2, xT);
    k_front<<<501, 256, 0, stream>>>(q, ek, xT, nh2, node_index,
                                     sws, sbs, swn, sbn, w_in, wsg,
                                     wadj, xa, base1, vecs);
    k_sage2<<<2000, 512, 0, stream>>>(base1, xa, vecs, node_index, wadj,
                                      wsg + 2048, sbs, sbn, mid);
    k_tcn<<<1000, 256, 0, stream>>>(mid, W2, tb1, tb2,
                                    wgate, bgate, wout, bout, out);
}

// Round 17
// 110.800 us; speedup vs baseline: 1.5741x; 1.0167x over previous
//
#include <hip/hip_runtime.h>
#include <math.h>

// Sizes: N=2000, M=32, H=64, EMB=32, F=32, T=12, B=4, HOR=12, K=2, DILS=(1,2)

// ---------------- K1: node MLP -> q, ek, nh2; also xT, TCN W2 pack, SAGE wpack ----
__global__ __launch_bounds__(256) void k_embed(
    const float* __restrict__ nf, const float* __restrict__ inputs,
    const float* __restrict__ w3, const float* __restrict__ b3,
    const float* __restrict__ w4, const float* __restrict__ b4,
    const float* __restrict__ w5, const float* __restrict__ b5,
    const float* __restrict__ wq, const float* __restrict__ wk,
    const float* __restrict__ wn, const float* __restrict__ bn,
    const float* __restrict__ b_in,
    const float* __restrict__ tw1, const float* __restrict__ tw2,
    const float* __restrict__ sws, const float* __restrict__ swn,
    float2* __restrict__ W2, float4* __restrict__ wsg,
    float* __restrict__ qo, float* __restrict__ eko, float* __restrict__ nho,
    float* __restrict__ xT)
{
    const int tid = threadIdx.x;
    if (tid < 192) {                                   // xT transpose: 500*192 = 96000
        const int id = blockIdx.x * 192 + tid;
        const int t = id / 8000, rem = id % 8000;
        const int b = rem / 2000, n2 = rem % 2000;
        xT[n2 * 48 + b * 12 + t] = inputs[id];
    }
    if (blockIdx.x < 64) {            // TCN weights -> [c][ig][o][ii]{k0,k1}, 16384 f2
        const int id = blockIdx.x * 256 + tid;
        const int c = id >> 12, r = id & 4095;
        const int ig = r >> 8, o = (r >> 2) & 63, ii = r & 3;
        const float* src = (c == 0) ? tw1 : (c == 1) ? tw2
                         : (c == 2) ? tw1 + 8192 : tw2 + 8192;
        const int i = ig * 4 + ii;
        W2[id] = make_float2(src[o * 128 + i * 2], src[o * 128 + i * 2 + 1]);
    } else if (blockIdx.x < 80) {                      // SAGE weights -> [l][k2][h] float4
        const int id = (blockIdx.x - 64) * 256 + tid;  // 0..4095
        const int l = id >> 11, rr = id & 2047;
        const int k2 = rr >> 6, h = rr & 63;
        const float* S = sws + l * 4096;
        const float* Nn = swn + l * 4096;
        wsg[id] = make_float4(S[(2 * k2) * 64 + h],     Nn[(2 * k2) * 64 + h],
                              S[(2 * k2 + 1) * 64 + h], Nn[(2 * k2 + 1) * 64 + h]);
    }
    const int lane = tid & 63;
    const int n = blockIdx.x * 4 + (tid >> 6);

    float nfv = 0.f;
    if (lane < 32) nfv = nf[n * 32 + lane];

    float e1 = b3[lane];
#pragma unroll
    for (int f = 0; f < 32; ++f)
        e1 = fmaf(__shfl(nfv, f), w3[f * 64 + lane], e1);
    e1 = fmaxf(e1, 0.f);

    float e2 = b4[lane];
#pragma unroll
    for (int f = 0; f < 64; ++f)
        e2 = fmaf(__shfl(e1, f), w4[f * 64 + lane], e2);
    e2 = fmaxf(e2, 0.f);

    const int c = lane & 31;
    float ev = b5[c];
#pragma unroll
    for (int f = 0; f < 64; ++f)
        ev = fmaf(__shfl(e2, f), w5[f * 32 + c], ev);

    float qv = 0.f, ekv = 0.f, nhv = bn[lane] + b_in[lane];
#pragma unroll
    for (int f = 0; f < 32; ++f) {
        float e = __shfl(ev, f);
        qv  = fmaf(e, wq[f * 64 + lane], qv);
        ekv = fmaf(e, wk[f * 64 + lane], ekv);
        nhv = fmaf(e, wn[f * 64 + lane], nhv);
    }
    qo [n * 64 + lane] = qv;
    eko[n * 64 + lane] = ekv;
    nho[n * 64 + lane] = nhv;
}

// ---------------- K2: fused scores+softmax -> wadj; ax -> xa; base1 (+vecs) ----
__global__ __launch_bounds__(256) void k_front(
    const float* __restrict__ q, const float* __restrict__ ek,
    const float* __restrict__ xT, const float* __restrict__ nh2,
    const int* __restrict__ nidx,
    const float* __restrict__ sws, const float* __restrict__ sbs,
    const float* __restrict__ swn, const float* __restrict__ sbn,
    const float* __restrict__ w_in, const float4* __restrict__ wsg,
    float* __restrict__ wadj, float2* __restrict__ xa,
    float* __restrict__ base1, float* __restrict__ vecs)
{
    const int tid = threadIdx.x;
    const int lane = tid & 63, wave = tid >> 6;
    if (blockIdx.x == 500) {
        if (wave == 0) {
            const float wv = w_in[lane];
            float s1 = 0.f, n1 = 0.f;
#pragma unroll
            for (int k = 0; k < 64; ++k) {
                const float wkk = __shfl(wv, k);
                s1 = fmaf(wkk, sws[k * 64 + lane], s1);
                n1 = fmaf(wkk, swn[k * 64 + lane], n1);
            }
            vecs[lane] = s1; vecs[64 + lane] = n1;
        }
        return;
    }
    __shared__ __align__(16) float2 pair[4][64];
    const int n = blockIdx.x * 4 + wave;

    int j = 0;
    if (lane < 32) j = nidx[n * 32 + lane];
    float w;
    {
        const float4* qr = (const float4*)(q + n * 64);
        const float4* er = (const float4*)(ek + j * 64);
        float s = 0.f;
#pragma unroll
        for (int u = 0; u < 16; ++u) {
            const float4 a = qr[u], b = er[u];
            s = fmaf(a.x, b.x, s); s = fmaf(a.y, b.y, s);
            s = fmaf(a.z, b.z, s); s = fmaf(a.w, b.w, s);
        }
        s *= 0.125f;
        float mx = s;
#pragma unroll
        for (int d = 16; d >= 1; d >>= 1) mx = fmaxf(mx, __shfl_xor(mx, d));
        const float ex = expf(s - mx);
        float sum = ex;
#pragma unroll
        for (int d = 16; d >= 1; d >>= 1) sum += __shfl_xor(sum, d);
        w = ex / sum;
        if (lane < 32) wadj[n * 32 + lane] = w;
    }
    float ax = 0.f, anh = 0.f;
    const bool act = lane < 48;
#pragma unroll 8
    for (int m = 0; m < 32; ++m) {
        const int jm = __shfl(j, m);
        const float wm = __shfl(w, m);
        const float xv = act ? xT[jm * 48 + lane] : 0.f;
        ax  = fmaf(wm, xv, ax);
        anh = fmaf(wm, nh2[jm * 64 + lane], anh);
    }
    if (act) xa[n * 48 + lane] = make_float2(xT[n * 48 + lane], ax);
    pair[wave][lane] = make_float2(nh2[n * 64 + lane], anh);
    __syncthreads();

    float acc = sbs[lane] + sbn[lane];
    const float2* pw = pair[wave];
#pragma unroll
    for (int k2 = 0; k2 < 32; ++k2) {
        const float4 wv = wsg[k2 * 64 + lane];
        const float4 sv = *(const float4*)(pw + k2 * 2);
        acc = fmaf(sv.x, wv.x, acc); acc = fmaf(sv.y, wv.y, acc);
        acc = fmaf(sv.z, wv.z, acc); acc = fmaf(sv.w, wv.w, acc);
    }
    base1[n * 64 + lane] = acc;
}

// ---------------- K3: fused SAGE layer 2 (recompute h1 from scalars) -> mid ----------
// __launch_bounds__(512,4): 128-VGPR budget. r16 showed (512,8) forced VGPR=32
// with ~23 MB scratch spill (WRITE_SIZE 47.9 vs 24.6 MB) -- same rule-#6 cliff
// as r13/r15. LDS 24.6 KB -> 4 blocks/CU (32 waves) at the wave cap.
__global__ __launch_bounds__(512, 4) void k_sage2(
    const float* __restrict__ base1, const float2* __restrict__ xa,
    const float* __restrict__ vecs,
    const int* __restrict__ nidx, const float* __restrict__ wadj,
    const float4* __restrict__ wsg2,
    const float* __restrict__ sbs, const float* __restrict__ sbn,
    float* __restrict__ mid)
{
    __shared__ __align__(16) float2 svp[48][64];        // {h1self, agg}, 24 KB
    const int tid = threadIdx.x, lane = tid & 63;
    const int wave = __builtin_amdgcn_readfirstlane(tid >> 6);
    const int n = blockIdx.x;
    const int bt0 = wave * 6;

    const float s1 = vecs[lane], n1 = vecs[64 + lane];
    const float bs = base1[n * 64 + lane];

    float agg[6] = {0.f, 0.f, 0.f, 0.f, 0.f, 0.f};
#pragma unroll 8
    for (int m = 0; m < 32; ++m) {
        const int j = nidx[n * 32 + m];                 // block-uniform -> s_load
        const float w = wadj[n * 32 + m];               // block-uniform -> s_load
        const float bj = base1[j * 64 + lane];
        const float4* xr = (const float4*)(xa + j * 48 + bt0);
        const float4 p0 = xr[0], p1 = xr[1], p2 = xr[2];
        float t;
        t = fmaf(p0.x, s1, fmaf(p0.y, n1, bj)); agg[0] = fmaf(w, fmaxf(t, 0.f), agg[0]);
        t = fmaf(p0.z, s1, fmaf(p0.w, n1, bj)); agg[1] = fmaf(w, fmaxf(t, 0.f), agg[1]);
        t = fmaf(p1.x, s1, fmaf(p1.y, n1, bj)); agg[2] = fmaf(w, fmaxf(t, 0.f), agg[2]);
        t = fmaf(p1.z, s1, fmaf(p1.w, n1, bj)); agg[3] = fmaf(w, fmaxf(t, 0.f), agg[3]);
        t = fmaf(p2.x, s1, fmaf(p2.y, n1, bj)); agg[4] = fmaf(w, fmaxf(t, 0.f), agg[4]);
        t = fmaf(p2.z, s1, fmaf(p2.w, n1, bj)); agg[5] = fmaf(w, fmaxf(t, 0.f), agg[5]);
    }
    {
        const float4* xs = (const float4*)(xa + n * 48 + bt0);
        const float4 q0 = xs[0], q1 = xs[1], q2 = xs[2];
        svp[bt0 + 0][lane] = make_float2(fmaxf(fmaf(q0.x, s1, fmaf(q0.y, n1, bs)), 0.f), agg[0]);
        svp[bt0 + 1][lane] = make_float2(fmaxf(fmaf(q0.z, s1, fmaf(q0.w, n1, bs)), 0.f), agg[1]);
        svp[bt0 + 2][lane] = make_float2(fmaxf(fmaf(q1.x, s1, fmaf(q1.y, n1, bs)), 0.f), agg[2]);
        svp[bt0 + 3][lane] = make_float2(fmaxf(fmaf(q1.z, s1, fmaf(q1.w, n1, bs)), 0.f), agg[3]);
        svp[bt0 + 4][lane] = make_float2(fmaxf(fmaf(q2.x, s1, fmaf(q2.y, n1, bs)), 0.f), agg[4]);
        svp[bt0 + 5][lane] = make_float2(fmaxf(fmaf(q2.z, s1, fmaf(q2.w, n1, bs)), 0.f), agg[5]);
    }
    const float b2 = sbs[64 + lane] + sbn[64 + lane];
    float acc[6] = {b2, b2, b2, b2, b2, b2};
    const float4* wp = wsg2 + lane;
    const float2* s0 = svp[bt0];
#pragma unroll
    for (int k2 = 0; k2 < 32; ++k2) {
        const float4 w4 = wp[k2 * 64];
        const float4 v0 = *(const float4*)(s0 + 0 * 64 + k2 * 2);
        const float4 v1 = *(const float4*)(s0 + 1 * 64 + k2 * 2);
        const float4 v2 = *(const float4*)(s0 + 2 * 64 + k2 * 2);
        const float4 v3 = *(const float4*)(s0 + 3 * 64 + k2 * 2);
        const float4 v4 = *(const float4*)(s0 + 4 * 64 + k2 * 2);
        const float4 v5 = *(const float4*)(s0 + 5 * 64 + k2 * 2);
        acc[0] = fmaf(v0.x, w4.x, fmaf(v0.y, w4.y, fmaf(v0.z, w4.z, fmaf(v0.w, w4.w, acc[0]))));
        acc[1] = fmaf(v1.x, w4.x, fmaf(v1.y, w4.y, fmaf(v1.z, w4.z, fmaf(v1.w, w4.w, acc[1]))));
        acc[2] = fmaf(v2.x, w4.x, fmaf(v2.y, w4.y, fmaf(v2.z, w4.z, fmaf(v2.w, w4.w, acc[2]))));
        acc[3] = fmaf(v3.x, w4.x, fmaf(v3.y, w4.y, fmaf(v3.z, w4.z, fmaf(v3.w, w4.w, acc[3]))));
        acc[4] = fmaf(v4.x, w4.x, fmaf(v4.y, w4.y, fmaf(v4.z, w4.z, fmaf(v4.w, w4.w, acc[4]))));
        acc[5] = fmaf(v5.x, w4.x, fmaf(v5.y, w4.y, fmaf(v5.z, w4.z, fmaf(v5.w, w4.w, acc[5]))));
    }
#pragma unroll
    for (int r = 0; r < 6; ++r)
        mid[((bt0 + r) * 2000 + n) * 64 + lane] = fmaxf(acc[r], 0.f);
}

// ---------------- K4: TCN seq-parallel GEMM, 256 thr / 4 waves / 8 seqs / 2 ch/lane ----
__global__ __launch_bounds__(256, 4) void k_tcn(
    const float* __restrict__ mid, const float2* __restrict__ W2,
    const float* __restrict__ tb1, const float* __restrict__ tb2,
    const float* __restrict__ wgate, const float* __restrict__ bgate,
    const float* __restrict__ wout, const float* __restrict__ bout,
    float* __restrict__ outp)
{
    __shared__ __align__(16) float xls[9][8][68];        // 19.1 KB
    const int tid = threadIdx.x, lane = tid & 63;
    const int wfl = __builtin_amdgcn_readfirstlane(tid >> 6);   // 0..3
    const int hg = (lane >> 3) & 7;
    const int s = lane & 7;
    const int bI = blockIdx.x / 250;                     // 250 blocks per b (2000/8)
    const int n0 = (blockIdx.x - bI * 250) * 8;
    const long base = ((long)(bI * 12) * 2000 + n0) * 64;
    const int obase = wfl * 16 + hg * 2;                 // 2 ch per lane
    const float4* __restrict__ Wf4 = (const float4*)W2;  // [(c*16+ig)*64+o]*2 {+0,+1}

    // ---- stage 0: stage x1[t=5..11] -> slots 0..6, layout [slot][s][ch]
    for (int e = tid; e < 896; e += 256) {
        const int u = e >> 7, rem = e & 127;
        const int ss = rem >> 4, qq = rem & 15;
        const float4 v = *(const float4*)(mid + base + (5 + u) * 128000L + ss * 64 + qq * 4);
        *(float4*)&xls[u][ss][qq * 4] = v;
    }
    __syncthreads();

    // ---- stage 1: l0 conv1 (D=1): y1[t=6..11]
    float y[2][6];
    {
        const float2 bv = *(const float2*)(tb1 + obase);
#pragma unroll
        for (int j = 0; j < 6; ++j) { y[0][j] = bv.x; y[1][j] = bv.y; }
    }
#pragma unroll 2
    for (int ig = 0; ig < 16; ++ig) {
        float4 xv[7];
#pragma unroll
        for (int u = 0; u < 7; ++u)
            xv[u] = *(const float4*)&xls[u][s][ig * 4];
#pragma unroll
        for (int oo = 0; oo < 2; ++oo) {
            const float4 wA = Wf4[(ig * 64 + obase + oo) * 2 + 0];
            const float4 wB = Wf4[(ig * 64 + obase + oo) * 2 + 1];
#pragma unroll
            for (int j = 0; j < 6; ++j) {
                float acc = y[oo][j];
                acc = fmaf(wA.x, xv[j].x, acc); acc = fmaf(wA.y, xv[j+1].x, acc);
                acc = fmaf(wA.z, xv[j].y, acc); acc = fmaf(wA.w, xv[j+1].y, acc);
                acc = fmaf(wB.x, xv[j].z, acc); acc = fmaf(wB.y, xv[j+1].z, acc);
                acc = fmaf(wB.z, xv[j].w, acc); acc = fmaf(wB.w, xv[j+1].w, acc);
                y[oo][j] = acc;
            }
        }
    }
    __syncthreads();                                     // all stage-1 reads done
    // y1 -> slots {0,1,7,3,8,5} (x1 slots 2,4,6 = residuals preserved)
    {
        const int S1OUT[6] = {0, 1, 7, 3, 8, 5};
#pragma unroll
        for (int j = 0; j < 6; ++j) {
            float2 o2;
            o2.x = fmaxf(y[0][j], 0.f); o2.y = fmaxf(y[1][j], 0.f);
            *(float2*)&xls[S1OUT[j]][s][obase] = o2;
        }
    }
    __syncthreads();

    // ---- stage 2: l0 conv2 (D=1) at t=7,9,11
    float a[2][3];
    {
        const float2 bv = *(const float2*)(tb2 + obase);
#pragma unroll
        for (int v = 0; v < 3; ++v) { a[0][v] = bv.x; a[1][v] = bv.y; }
    }
#pragma unroll 2
    for (int ig = 0; ig < 16; ++ig) {
        const float4 y0 = *(const float4*)&xls[0][s][ig * 4];   // y1@6
        const float4 y1v = *(const float4*)&xls[1][s][ig * 4];  // y1@7
        const float4 y2 = *(const float4*)&xls[7][s][ig * 4];   // y1@8
        const float4 y3v = *(const float4*)&xls[3][s][ig * 4];  // y1@9
        const float4 y4 = *(const float4*)&xls[8][s][ig * 4];   // y1@10
        const float4 y5 = *(const float4*)&xls[5][s][ig * 4];   // y1@11
#pragma unroll
        for (int oo = 0; oo < 2; ++oo) {
            const float4 wA = Wf4[((16 + ig) * 64 + obase + oo) * 2 + 0];
            const float4 wB = Wf4[((16 + ig) * 64 + obase + oo) * 2 + 1];
            float t0 = a[oo][0], t1 = a[oo][1], t2 = a[oo][2];
            t0 = fmaf(wA.x, y0.x, t0);  t0 = fmaf(wA.y, y1v.x, t0);
            t0 = fmaf(wA.z, y0.y, t0);  t0 = fmaf(wA.w, y1v.y, t0);
            t0 = fmaf(wB.x, y0.z, t0);  t0 = fmaf(wB.y, y1v.z, t0);
            t0 = fmaf(wB.z, y0.w, t0);  t0 = fmaf(wB.w, y1v.w, t0);
            t1 = fmaf(wA.x, y2.x, t1);  t1 = fmaf(wA.y, y3v.x, t1);
            t1 = fmaf(wA.z, y2.y, t1);  t1 = fmaf(wA.w, y3v.y, t1);
            t1 = fmaf(wB.x, y2.z, t1);  t1 = fmaf(wB.y, y3v.z, t1);
            t1 = fmaf(wB.z, y2.w, t1);  t1 = fmaf(wB.w, y3v.w, t1);
            t2 = fmaf(wA.x, y4.x, t2);  t2 = fmaf(wA.y, y5.x, t2);
            t2 = fmaf(wA.z, y4.y, t2);  t2 = fmaf(wA.w, y5.y, t2);
            t2 = fmaf(wB.x, y4.z, t2);  t2 = fmaf(wB.y, y5.z, t2);
            t2 = fmaf(wB.z, y4.w, t2);  t2 = fmaf(wB.w, y5.w, t2);
            a[oo][0] = t0; a[oo][1] = t1; a[oo][2] = t2;
        }
    }
    __syncthreads();                                     // stage-2 reads done
    // x2[t] = relu(relu(a) + x1[t]) -> slots {0,1,7}; residuals slots {2,4,6}
    {
        const int RIN[3] = {2, 4, 6}, ROUT[3] = {0, 1, 7};
#pragma unroll
        for (int v = 0; v < 3; ++v) {
            const float2 xr = *(const float2*)&xls[RIN[v]][s][obase];
            float2 o2;
            o2.x = fmaxf(fmaxf(a[0][v], 0.f) + xr.x, 0.f);
            o2.y = fmaxf(fmaxf(a[1][v], 0.f) + xr.y, 0.f);
            *(float2*)&xls[ROUT[v]][s][obase] = o2;
        }
    }
    __syncthreads();

    // ---- stage 3: l1 conv1 (D=2) at t=9,11; x2 slots {0,1,7}
    float d[2][2];
    {
        const float2 bv = *(const float2*)(tb1 + 64 + obase);
        d[0][0] = bv.x; d[0][1] = bv.x; d[1][0] = bv.y; d[1][1] = bv.y;
    }
#pragma unroll 2
    for (int ig = 0; ig < 16; ++ig) {
        const float4 x0 = *(const float4*)&xls[0][s][ig * 4];   // x2@7
        const float4 x1 = *(const float4*)&xls[1][s][ig * 4];   // x2@9
        const float4 x2 = *(const float4*)&xls[7][s][ig * 4];   // x2@11
#pragma unroll
        for (int oo = 0; oo < 2; ++oo) {
            const float4 wA = Wf4[((32 + ig) * 64 + obase + oo) * 2 + 0];
            const float4 wB = Wf4[((32 + ig) * 64 + obase + oo) * 2 + 1];
            float t0 = d[oo][0], t1 = d[oo][1];
            t0 = fmaf(wA.x, x0.x, t0);  t0 = fmaf(wA.y, x1.x, t0);
            t0 = fmaf(wA.z, x0.y, t0);  t0 = fmaf(wA.w, x1.y, t0);
            t0 = fmaf(wB.x, x0.z, t0);  t0 = fmaf(wB.y, x1.z, t0);
            t0 = fmaf(wB.z, x0.w, t0);  t0 = fmaf(wB.w, x1.w, t0);
            t1 = fmaf(wA.x, x1.x, t1);  t1 = fmaf(wA.y, x2.x, t1);
            t1 = fmaf(wA.z, x1.y, t1);  t1 = fmaf(wA.w, x2.y, t1);
            t1 = fmaf(wB.x, x1.z, t1);  t1 = fmaf(wB.y, x2.z, t1);
            t1 = fmaf(wB.z, x1.w, t1);  t1 = fmaf(wB.w, x2.w, t1);
            d[oo][0] = t0; d[oo][1] = t1;
        }
    }
    // y3 -> slots {3,8} (y1 dead; stage-3 reads only {0,1,7})
    {
        float2 o2;
        o2.x = fmaxf(d[0][0], 0.f); o2.y = fmaxf(d[1][0], 0.f);
        *(float2*)&xls[3][s][obase] = o2;                // y3@9
        o2.x = fmaxf(d[0][1], 0.f); o2.y = fmaxf(d[1][1], 0.f);
        *(float2*)&xls[8][s][obase] = o2;                // y3@11
    }
    __syncthreads();

    // ---- stage 4: l1 conv2 (D=2) at t=11; y3 slots {3,8}
    float f[2];
    {
        const float2 bv = *(const float2*)(tb2 + 64 + obase);
        f[0] = bv.x; f[1] = bv.y;
    }
#pragma unroll 2
    for (int ig = 0; ig < 16; ++ig) {
        const float4 g0 = *(const float4*)&xls[3][s][ig * 4];   // y3@9
        const float4 g1 = *(const float4*)&xls[8][s][ig * 4];   // y3@11
#pragma unroll
        for (int oo = 0; oo < 2; ++oo) {
            const float4 wA = Wf4[((48 + ig) * 64 + obase + oo) * 2 + 0];
            const float4 wB = Wf4[((48 + ig) * 64 + obase + oo) * 2 + 1];
            float t0 = f[oo];
            t0 = fmaf(wA.x, g0.x, t0);  t0 = fmaf(wA.y, g1.x, t0);
            t0 = fmaf(wA.z, g0.y, t0);  t0 = fmaf(wA.w, g1.y, t0);
            t0 = fmaf(wB.x, g0.z, t0);  t0 = fmaf(wB.y, g1.z, t0);
            t0 = fmaf(wB.z, g0.w, t0);  t0 = fmaf(wB.w, g1.w, t0);
            f[oo] = t0;
        }
    }
    // ht = relu(relu(f) + x2@11)
    float ht[2];
    {
        const float2 xr = *(const float2*)&xls[7][s][obase];
        ht[0] = fmaxf(fmaxf(f[0], 0.f) + xr.x, 0.f);
        ht[1] = fmaxf(fmaxf(f[1], 0.f) + xr.y, 0.f);
    }

    // ---- epilogue: gate (cross-hg shfl strides 8..32 + cross-wave LDS)
    float* pbuf = &xls[2][0][0];                         // slot 2 free now
    {
        const float2 wg2 = *(const float2*)(wgate + obase);
        float p = ht[0] * wg2.x + ht[1] * wg2.y;
        p += __shfl_xor(p, 8); p += __shfl_xor(p, 16); p += __shfl_xor(p, 32);
        if (hg == 0) pbuf[wfl * 8 + s] = p;
    }
    __syncthreads();
    float ptot = 0.f;
#pragma unroll
    for (int w4i = 0; w4i < 4; ++w4i) ptot += pbuf[w4i * 8 + s];
    const float g = 1.f / (1.f + expf(-(ptot + bgate[0])));
    float fo[2];
    {
        const float2 hs = *(const float2*)&xls[6][s][obase];   // x1@11
        fo[0] = g * ht[0] + (1.f - g) * hs.x;
        fo[1] = g * ht[1] + (1.f - g) * hs.y;
    }
    float po[12];
#pragma unroll
    for (int h2 = 0; h2 < 12; ++h2) po[h2] = 0.f;
#pragma unroll
    for (int oo = 0; oo < 2; ++oo) {
        const float* wr = wout + (obase + oo) * 12;
        const float4 w0 = *(const float4*)(wr);
        const float4 w1 = *(const float4*)(wr + 4);
        const float4 w2 = *(const float4*)(wr + 8);
        po[0] = fmaf(fo[oo], w0.x, po[0]);  po[1] = fmaf(fo[oo], w0.y, po[1]);
        po[2] = fmaf(fo[oo], w0.z, po[2]);  po[3] = fmaf(fo[oo], w0.w, po[3]);
        po[4] = fmaf(fo[oo], w1.x, po[4]);  po[5] = fmaf(fo[oo], w1.y, po[5]);
        po[6] = fmaf(fo[oo], w1.z, po[6]);  po[7] = fmaf(fo[oo], w1.w, po[7]);
        po[8] = fmaf(fo[oo], w2.x, po[8]);  po[9] = fmaf(fo[oo], w2.y, po[9]);
        po[10] = fmaf(fo[oo], w2.z, po[10]); po[11] = fmaf(fo[oo], w2.w, po[11]);
    }
#pragma unroll
    for (int h2 = 0; h2 < 12; ++h2) {
        po[h2] += __shfl_xor(po[h2], 8);
        po[h2] += __shfl_xor(po[h2], 16);
        po[h2] += __shfl_xor(po[h2], 32);
    }
    float* pobuf = &xls[4][0][0];                        // slots 4-5 free (1088 f)
    if (hg == 0) {
#pragma unroll
        for (int h2 = 0; h2 < 12; ++h2)
            pobuf[(wfl * 12 + h2) * 8 + s] = po[h2];
    }
    __syncthreads();
    if (tid < 96) {
        const int h2 = tid >> 3, sq = tid & 7;
        float r = bout[h2];
#pragma unroll
        for (int w4i = 0; w4i < 4; ++w4i)
            r += pobuf[(w4i * 12 + h2) * 8 + sq];
        outp[h2 * 8000 + bI * 2000 + n0 + sq] = r;
    }
}

extern "C" void kernel_launch(void* const* d_in, const int* in_sizes, int n_in,
                              void* d_out, int out_size, void* d_ws, size_t ws_size,
                              hipStream_t stream) {
    const float* inputs     = (const float*)d_in[0];
    const float* node_feas  = (const float*)d_in[1];
    const int*   node_index = (const int*)  d_in[2];
    const float* w_fc3 = (const float*)d_in[3];
    const float* b_fc3 = (const float*)d_in[4];
    const float* w_fc4 = (const float*)d_in[5];
    const float* b_fc4 = (const float*)d_in[6];
    const float* w_fc5 = (const float*)d_in[7];
    const float* b_fc5 = (const float*)d_in[8];
    const float* w_nhp = (const float*)d_in[9];
    const float* b_nhp = (const float*)d_in[10];
    const float* w_q   = (const float*)d_in[11];
    const float* w_k   = (const float*)d_in[12];
    const float* w_in  = (const float*)d_in[13];
    const float* b_in  = (const float*)d_in[14];
    const float* sws   = (const float*)d_in[15];
    const float* sbs   = (const float*)d_in[16];
    const float* swn   = (const float*)d_in[17];
    const float* sbn   = (const float*)d_in[18];
    const float* tw1   = (const float*)d_in[19];
    const float* tb1   = (const float*)d_in[20];
    const float* tw2   = (const float*)d_in[21];
    const float* tb2   = (const float*)d_in[22];
    const float* wgate = (const float*)d_in[23];
    const float* bgate = (const float*)d_in[24];
    const float* wout  = (const float*)d_in[25];
    const float* bout  = (const float*)d_in[26];

    float* out  = (float*)d_out;           // (12,4,2000)        96000
    float* mid  = out + 96000;             // (4,12,2000,64)     6144000
    float* wadj = mid + 6144000;           // (2000,32)          64000

    float*  q     = (float*)d_ws;          // 128000
    float*  ek    = q     + 128000;        // 128000
    float*  nh2   = ek    + 128000;        // 128000 (includes b_nhp + b_in)
    float*  base1 = nh2   + 128000;        // 128000
    float*  xT    = base1 + 128000;        // 96000   [n][bt]
    float2* xa    = (float2*)(xT + 96000); // 96000 float2 {x, ax}
    float*  vecs  = xT + 96000 + 192000;   // 128 {s1v, n1v}
    float2* W2    = (float2*)(vecs + 128); // 16384 float2 (TCN weights [c][ig][o][ii])
    float4* wsg   = (float4*)(vecs + 128 + 32768);  // 4096 float4 (SAGE packed)

    k_embed<<<500, 256, 0, stream>>>(node_feas, inputs, w_fc3, b_fc3, w_fc4, b_fc4,
                                     w_fc5, b_fc5, w_q, w_k, w_nhp, b_nhp, b_in,
                                     tw1, tw2, sws, swn, W2, wsg,
                                     q, ek, nh2, xT);
    k_front<<<501, 256, 0, stream>>>(q, ek, xT, nh2, node_index,
                                     sws, sbs, swn, sbn, w_in, wsg,
                                     wadj, xa, base1, vecs);
    k_sage2<<<2000, 512, 0, stream>>>(base1, xa, vecs, node_index, wadj,
                                      wsg + 2048, sbs, sbn, mid);
    k_tcn<<<1000, 256, 0, stream>>>(mid, W2, tb1, tb2,
                                    wgate, bgate, wout, bout, out);
}

// Round 18
// 110.572 us; speedup vs baseline: 1.5774x; 1.0021x over previous
//
#include <hip/hip_runtime.h>
#include <math.h>

// Sizes: N=2000, M=32, H=64, EMB=32, F=32, T=12, B=4, HOR=12, K=2, DILS=(1,2)

// ---------------- K1: node MLP -> q, ek, nh2; also xT, TCN Wt pack, SAGE wpack ----
// TCN weights packed PER-OUTPUT-CHANNEL contiguous: Wt4[o][c][ig][{wA,wB}]
// (2 KB per o) so k_tcn's per-thread weight stream is base+immediate only.
__global__ __launch_bounds__(256) void k_embed(
    const float* __restrict__ nf, const float* __restrict__ inputs,
    const float* __restrict__ w3, const float* __restrict__ b3,
    const float* __restrict__ w4, const float* __restrict__ b4,
    const float* __restrict__ w5, const float* __restrict__ b5,
    const float* __restrict__ wq, const float* __restrict__ wk,
    const float* __restrict__ wn, const float* __restrict__ bn,
    const float* __restrict__ b_in,
    const float* __restrict__ tw1, const float* __restrict__ tw2,
    const float* __restrict__ sws, const float* __restrict__ swn,
    float2* __restrict__ W2, float4* __restrict__ wsg,
    float* __restrict__ qo, float* __restrict__ eko, float* __restrict__ nho,
    float* __restrict__ xT)
{
    const int tid = threadIdx.x;
    if (tid < 192) {                                   // xT transpose: 500*192 = 96000
        const int id = blockIdx.x * 192 + tid;
        const int t = id / 8000, rem = id % 8000;
        const int b = rem / 2000, n2 = rem % 2000;
        xT[n2 * 48 + b * 12 + t] = inputs[id];
    }
    if (blockIdx.x < 64) {            // TCN weights -> [o][c][ig][half][pr] 16384 f2
        const int id = blockIdx.x * 256 + tid;
        const int pr = id & 1, half = (id >> 1) & 1;
        const int ig = (id >> 2) & 15, c = (id >> 6) & 3, o = id >> 8;
        const float* src = (c == 0) ? tw1 : (c == 1) ? tw2
                         : (c == 2) ? tw1 + 8192 : tw2 + 8192;
        const int i = ig * 4 + half * 2 + pr;
        W2[id] = make_float2(src[o * 128 + i * 2], src[o * 128 + i * 2 + 1]);
    } else if (blockIdx.x < 80) {                      // SAGE weights -> [l][k2][h] float4
        const int id = (blockIdx.x - 64) * 256 + tid;  // 0..4095
        const int l = id >> 11, rr = id & 2047;
        const int k2 = rr >> 6, h = rr & 63;
        const float* S = sws + l * 4096;
        const float* Nn = swn + l * 4096;
        wsg[id] = make_float4(S[(2 * k2) * 64 + h],     Nn[(2 * k2) * 64 + h],
                              S[(2 * k2 + 1) * 64 + h], Nn[(2 * k2 + 1) * 64 + h]);
    }
    const int lane = tid & 63;
    const int n = blockIdx.x * 4 + (tid >> 6);

    float nfv = 0.f;
    if (lane < 32) nfv = nf[n * 32 + lane];

    float e1 = b3[lane];
#pragma unroll
    for (int f = 0; f < 32; ++f)
        e1 = fmaf(__shfl(nfv, f), w3[f * 64 + lane], e1);
    e1 = fmaxf(e1, 0.f);

    float e2 = b4[lane];
#pragma unroll
    for (int f = 0; f < 64; ++f)
        e2 = fmaf(__shfl(e1, f), w4[f * 64 + lane], e2);
    e2 = fmaxf(e2, 0.f);

    const int c = lane & 31;
    float ev = b5[c];
#pragma unroll
    for (int f = 0; f < 64; ++f)
        ev = fmaf(__shfl(e2, f), w5[f * 32 + c], ev);

    float qv = 0.f, ekv = 0.f, nhv = bn[lane] + b_in[lane];
#pragma unroll
    for (int f = 0; f < 32; ++f) {
        float e = __shfl(ev, f);
        qv  = fmaf(e, wq[f * 64 + lane], qv);
        ekv = fmaf(e, wk[f * 64 + lane], ekv);
        nhv = fmaf(e, wn[f * 64 + lane], nhv);
    }
    qo [n * 64 + lane] = qv;
    eko[n * 64 + lane] = ekv;
    nho[n * 64 + lane] = nhv;
}

// ---------------- K2: fused scores+softmax -> wadj; ax -> xa; base1 (+vecs) ----
__global__ __launch_bounds__(256) void k_front(
    const float* __restrict__ q, const float* __restrict__ ek,
    const float* __restrict__ xT, const float* __restrict__ nh2,
    const int* __restrict__ nidx,
    const float* __restrict__ sws, const float* __restrict__ sbs,
    const float* __restrict__ swn, const float* __restrict__ sbn,
    const float* __restrict__ w_in, const float4* __restrict__ wsg,
    float* __restrict__ wadj, float2* __restrict__ xa,
    float* __restrict__ base1, float* __restrict__ vecs)
{
    const int tid = threadIdx.x;
    const int lane = tid & 63, wave = tid >> 6;
    if (blockIdx.x == 500) {
        if (wave == 0) {
            const float wv = w_in[lane];
            float s1 = 0.f, n1 = 0.f;
#pragma unroll
            for (int k = 0; k < 64; ++k) {
                const float wkk = __shfl(wv, k);
                s1 = fmaf(wkk, sws[k * 64 + lane], s1);
                n1 = fmaf(wkk, swn[k * 64 + lane], n1);
            }
            vecs[lane] = s1; vecs[64 + lane] = n1;
        }
        return;
    }
    __shared__ __align__(16) float2 pair[4][64];
    const int n = blockIdx.x * 4 + wave;

    int j = 0;
    if (lane < 32) j = nidx[n * 32 + lane];
    float w;
    {
        const float4* qr = (const float4*)(q + n * 64);
        const float4* er = (const float4*)(ek + j * 64);
        float s = 0.f;
#pragma unroll
        for (int u = 0; u < 16; ++u) {
            const float4 a = qr[u], b = er[u];
            s = fmaf(a.x, b.x, s); s = fmaf(a.y, b.y, s);
            s = fmaf(a.z, b.z, s); s = fmaf(a.w, b.w, s);
        }
        s *= 0.125f;
        float mx = s;
#pragma unroll
        for (int d = 16; d >= 1; d >>= 1) mx = fmaxf(mx, __shfl_xor(mx, d));
        const float ex = expf(s - mx);
        float sum = ex;
#pragma unroll
        for (int d = 16; d >= 1; d >>= 1) sum += __shfl_xor(sum, d);
        w = ex / sum;
        if (lane < 32) wadj[n * 32 + lane] = w;
    }
    float ax = 0.f, anh = 0.f;
    const bool act = lane < 48;
#pragma unroll 8
    for (int m = 0; m < 32; ++m) {
        const int jm = __shfl(j, m);
        const float wm = __shfl(w, m);
        const float xv = act ? xT[jm * 48 + lane] : 0.f;
        ax  = fmaf(wm, xv, ax);
        anh = fmaf(wm, nh2[jm * 64 + lane], anh);
    }
    if (act) xa[n * 48 + lane] = make_float2(xT[n * 48 + lane], ax);
    pair[wave][lane] = make_float2(nh2[n * 64 + lane], anh);
    __syncthreads();

    float acc = sbs[lane] + sbn[lane];
    const float2* pw = pair[wave];
#pragma unroll
    for (int k2 = 0; k2 < 32; ++k2) {
        const float4 wv = wsg[k2 * 64 + lane];
        const float4 sv = *(const float4*)(pw + k2 * 2);
        acc = fmaf(sv.x, wv.x, acc); acc = fmaf(sv.y, wv.y, acc);
        acc = fmaf(sv.z, wv.z, acc); acc = fmaf(sv.w, wv.w, acc);
    }
    base1[n * 64 + lane] = acc;
}

// ---------------- K3: fused SAGE layer 2 (recompute h1 from scalars) -> mid ----------
__global__ __launch_bounds__(512, 4) void k_sage2(
    const float* __restrict__ base1, const float2* __restrict__ xa,
    const float* __restrict__ vecs,
    const int* __restrict__ nidx, const float* __restrict__ wadj,
    const float4* __restrict__ wsg2,
    const float* __restrict__ sbs, const float* __restrict__ sbn,
    float* __restrict__ mid)
{
    __shared__ __align__(16) float2 svp[48][64];        // {h1self, agg}, 24 KB
    const int tid = threadIdx.x, lane = tid & 63;
    const int wave = __builtin_amdgcn_readfirstlane(tid >> 6);
    const int n = blockIdx.x;
    const int bt0 = wave * 6;

    const float s1 = vecs[lane], n1 = vecs[64 + lane];
    const float bs = base1[n * 64 + lane];

    float agg[6] = {0.f, 0.f, 0.f, 0.f, 0.f, 0.f};
#pragma unroll 8
    for (int m = 0; m < 32; ++m) {
        const int j = nidx[n * 32 + m];                 // block-uniform -> s_load
        const float w = wadj[n * 32 + m];               // block-uniform -> s_load
        const float bj = base1[j * 64 + lane];
        const float4* xr = (const float4*)(xa + j * 48 + bt0);
        const float4 p0 = xr[0], p1 = xr[1], p2 = xr[2];
        float t;
        t = fmaf(p0.x, s1, fmaf(p0.y, n1, bj)); agg[0] = fmaf(w, fmaxf(t, 0.f), agg[0]);
        t = fmaf(p0.z, s1, fmaf(p0.w, n1, bj)); agg[1] = fmaf(w, fmaxf(t, 0.f), agg[1]);
        t = fmaf(p1.x, s1, fmaf(p1.y, n1, bj)); agg[2] = fmaf(w, fmaxf(t, 0.f), agg[2]);
        t = fmaf(p1.z, s1, fmaf(p1.w, n1, bj)); agg[3] = fmaf(w, fmaxf(t, 0.f), agg[3]);
        t = fmaf(p2.x, s1, fmaf(p2.y, n1, bj)); agg[4] = fmaf(w, fmaxf(t, 0.f), agg[4]);
        t = fmaf(p2.z, s1, fmaf(p2.w, n1, bj)); agg[5] = fmaf(w, fmaxf(t, 0.f), agg[5]);
    }
    {
        const float4* xs = (const float4*)(xa + n * 48 + bt0);
        const float4 q0 = xs[0], q1 = xs[1], q2 = xs[2];
        svp[bt0 + 0][lane] = make_float2(fmaxf(fmaf(q0.x, s1, fmaf(q0.y, n1, bs)), 0.f), agg[0]);
        svp[bt0 + 1][lane] = make_float2(fmaxf(fmaf(q0.z, s1, fmaf(q0.w, n1, bs)), 0.f), agg[1]);
        svp[bt0 + 2][lane] = make_float2(fmaxf(fmaf(q1.x, s1, fmaf(q1.y, n1, bs)), 0.f), agg[2]);
        svp[bt0 + 3][lane] = make_float2(fmaxf(fmaf(q1.z, s1, fmaf(q1.w, n1, bs)), 0.f), agg[3]);
        svp[bt0 + 4][lane] = make_float2(fmaxf(fmaf(q2.x, s1, fmaf(q2.y, n1, bs)), 0.f), agg[4]);
        svp[bt0 + 5][lane] = make_float2(fmaxf(fmaf(q2.z, s1, fmaf(q2.w, n1, bs)), 0.f), agg[5]);
    }
    const float b2 = sbs[64 + lane] + sbn[64 + lane];
    float acc[6] = {b2, b2, b2, b2, b2, b2};
    const float4* wp = wsg2 + lane;
    const float2* s0 = svp[bt0];
#pragma unroll
    for (int k2 = 0; k2 < 32; ++k2) {
        const float4 w4 = wp[k2 * 64];
        const float4 v0 = *(const float4*)(s0 + 0 * 64 + k2 * 2);
        const float4 v1 = *(const float4*)(s0 + 1 * 64 + k2 * 2);
        const float4 v2 = *(const float4*)(s0 + 2 * 64 + k2 * 2);
        const float4 v3 = *(const float4*)(s0 + 3 * 64 + k2 * 2);
        const float4 v4 = *(const float4*)(s0 + 4 * 64 + k2 * 2);
        const float4 v5 = *(const float4*)(s0 + 5 * 64 + k2 * 2);
        acc[0] = fmaf(v0.x, w4.x, fmaf(v0.y, w4.y, fmaf(v0.z, w4.z, fmaf(v0.w, w4.w, acc[0]))));
        acc[1] = fmaf(v1.x, w4.x, fmaf(v1.y, w4.y, fmaf(v1.z, w4.z, fmaf(v1.w, w4.w, acc[1]))));
        acc[2] = fmaf(v2.x, w4.x, fmaf(v2.y, w4.y, fmaf(v2.z, w4.z, fmaf(v2.w, w4.w, acc[2]))));
        acc[3] = fmaf(v3.x, w4.x, fmaf(v3.y, w4.y, fmaf(v3.z, w4.z, fmaf(v3.w, w4.w, acc[3]))));
        acc[4] = fmaf(v4.x, w4.x, fmaf(v4.y, w4.y, fmaf(v4.z, w4.z, fmaf(v4.w, w4.w, acc[4]))));
        acc[5] = fmaf(v5.x, w4.x, fmaf(v5.y, w4.y, fmaf(v5.z, w4.z, fmaf(v5.w, w4.w, acc[5]))));
    }
#pragma unroll
    for (int r = 0; r < 6; ++r)
        mid[((bt0 + r) * 2000 + n) * 64 + lane] = fmaxf(acc[r], 0.f);
}

// ---------------- K4: TCN seq-parallel GEMM, 256 thr / 4 waves / 8 seqs / 2 ch/lane ----
// Weights: Wt4[o][c][ig][{wA,wB}] -- per-thread streams w0p/w1p are contiguous
// 2 KB, so all 256 weight loads are base+immediate (offset <= 2032 B).
__global__ __launch_bounds__(256, 4) void k_tcn(
    const float* __restrict__ mid, const float2* __restrict__ W2,
    const float* __restrict__ tb1, const float* __restrict__ tb2,
    const float* __restrict__ wgate, const float* __restrict__ bgate,
    const float* __restrict__ wout, const float* __restrict__ bout,
    float* __restrict__ outp)
{
    __shared__ __align__(16) float xls[9][8][68];        // 19.1 KB
    const int tid = threadIdx.x, lane = tid & 63;
    const int wfl = __builtin_amdgcn_readfirstlane(tid >> 6);   // 0..3
    const int hg = (lane >> 3) & 7;
    const int s = lane & 7;
    const int bI = blockIdx.x / 250;                     // 250 blocks per b (2000/8)
    const int n0 = (blockIdx.x - bI * 250) * 8;
    const long base = ((long)(bI * 12) * 2000 + n0) * 64;
    const int obase = wfl * 16 + hg * 2;                 // 2 ch per lane
    const float4* __restrict__ w0p = (const float4*)W2 + (obase + 0) * 128;
    const float4* __restrict__ w1p = (const float4*)W2 + (obase + 1) * 128;

    // ---- stage 0: stage x1[t=5..11] -> slots 0..6, layout [slot][s][ch]
    for (int e = tid; e < 896; e += 256) {
        const int u = e >> 7, rem = e & 127;
        const int ss = rem >> 4, qq = rem & 15;
        const float4 v = *(const float4*)(mid + base + (5 + u) * 128000L + ss * 64 + qq * 4);
        *(float4*)&xls[u][ss][qq * 4] = v;
    }
    __syncthreads();

    // ---- stage 1: l0 conv1 (D=1): y1[t=6..11]   (c=0: offsets 0..31)
    float y[2][6];
    {
        const float2 bv = *(const float2*)(tb1 + obase);
#pragma unroll
        for (int j = 0; j < 6; ++j) { y[0][j] = bv.x; y[1][j] = bv.y; }
    }
#pragma unroll 2
    for (int ig = 0; ig < 16; ++ig) {
        float4 xv[7];
#pragma unroll
        for (int u = 0; u < 7; ++u)
            xv[u] = *(const float4*)&xls[u][s][ig * 4];
#pragma unroll
        for (int oo = 0; oo < 2; ++oo) {
            const float4* wp = oo ? w1p : w0p;
            const float4 wA = wp[ig * 2 + 0];
            const float4 wB = wp[ig * 2 + 1];
#pragma unroll
            for (int j = 0; j < 6; ++j) {
                float acc = y[oo][j];
                acc = fmaf(wA.x, xv[j].x, acc); acc = fmaf(wA.y, xv[j+1].x, acc);
                acc = fmaf(wA.z, xv[j].y, acc); acc = fmaf(wA.w, xv[j+1].y, acc);
                acc = fmaf(wB.x, xv[j].z, acc); acc = fmaf(wB.y, xv[j+1].z, acc);
                acc = fmaf(wB.z, xv[j].w, acc); acc = fmaf(wB.w, xv[j+1].w, acc);
                y[oo][j] = acc;
            }
        }
    }
    __syncthreads();                                     // all stage-1 reads done
    // y1 -> slots {0,1,7,3,8,5} (x1 slots 2,4,6 = residuals preserved)
    {
        const int S1OUT[6] = {0, 1, 7, 3, 8, 5};
#pragma unroll
        for (int j = 0; j < 6; ++j) {
            float2 o2;
            o2.x = fmaxf(y[0][j], 0.f); o2.y = fmaxf(y[1][j], 0.f);
            *(float2*)&xls[S1OUT[j]][s][obase] = o2;
        }
    }
    __syncthreads();

    // ---- stage 2: l0 conv2 (D=1) at t=7,9,11   (c=1: offsets 32..63)
    float a[2][3];
    {
        const float2 bv = *(const float2*)(tb2 + obase);
#pragma unroll
        for (int v = 0; v < 3; ++v) { a[0][v] = bv.x; a[1][v] = bv.y; }
    }
#pragma unroll 2
    for (int ig = 0; ig < 16; ++ig) {
        const float4 y0 = *(const float4*)&xls[0][s][ig * 4];   // y1@6
        const float4 y1v = *(const float4*)&xls[1][s][ig * 4];  // y1@7
        const float4 y2 = *(const float4*)&xls[7][s][ig * 4];   // y1@8
        const float4 y3v = *(const float4*)&xls[3][s][ig * 4];  // y1@9
        const float4 y4 = *(const float4*)&xls[8][s][ig * 4];   // y1@10
        const float4 y5 = *(const float4*)&xls[5][s][ig * 4];   // y1@11
#pragma unroll
        for (int oo = 0; oo < 2; ++oo) {
            const float4* wp = oo ? w1p : w0p;
            const float4 wA = wp[32 + ig * 2 + 0];
            const float4 wB = wp[32 + ig * 2 + 1];
            float t0 = a[oo][0], t1 = a[oo][1], t2 = a[oo][2];
            t0 = fmaf(wA.x, y0.x, t0);  t0 = fmaf(wA.y, y1v.x, t0);
            t0 = fmaf(wA.z, y0.y, t0);  t0 = fmaf(wA.w, y1v.y, t0);
            t0 = fmaf(wB.x, y0.z, t0);  t0 = fmaf(wB.y, y1v.z, t0);
            t0 = fmaf(wB.z, y0.w, t0);  t0 = fmaf(wB.w, y1v.w, t0);
            t1 = fmaf(wA.x, y2.x, t1);  t1 = fmaf(wA.y, y3v.x, t1);
            t1 = fmaf(wA.z, y2.y, t1);  t1 = fmaf(wA.w, y3v.y, t1);
            t1 = fmaf(wB.x, y2.z, t1);  t1 = fmaf(wB.y, y3v.z, t1);
            t1 = fmaf(wB.z, y2.w, t1);  t1 = fmaf(wB.w, y3v.w, t1);
            t2 = fmaf(wA.x, y4.x, t2);  t2 = fmaf(wA.y, y5.x, t2);
            t2 = fmaf(wA.z, y4.y, t2);  t2 = fmaf(wA.w, y5.y, t2);
            t2 = fmaf(wB.x, y4.z, t2);  t2 = fmaf(wB.y, y5.z, t2);
            t2 = fmaf(wB.z, y4.w, t2);  t2 = fmaf(wB.w, y5.w, t2);
            a[oo][0] = t0; a[oo][1] = t1; a[oo][2] = t2;
        }
    }
    __syncthreads();                                     // stage-2 reads done
    // x2[t] = relu(relu(a) + x1[t]) -> slots {0,1,7}; residuals slots {2,4,6}
    {
        const int RIN[3] = {2, 4, 6}, ROUT[3] = {0, 1, 7};
#pragma unroll
        for (int v = 0; v < 3; ++v) {
            const float2 xr = *(const float2*)&xls[RIN[v]][s][obase];
            float2 o2;
            o2.x = fmaxf(fmaxf(a[0][v], 0.f) + xr.x, 0.f);
            o2.y = fmaxf(fmaxf(a[1][v], 0.f) + xr.y, 0.f);
            *(float2*)&xls[ROUT[v]][s][obase] = o2;
        }
    }
    __syncthreads();

    // ---- stage 3: l1 conv1 (D=2) at t=9,11; x2 slots {0,1,7}  (c=2: 64..95)
    float d[2][2];
    {
        const float2 bv = *(const float2*)(tb1 + 64 + obase);
        d[0][0] = bv.x; d[0][1] = bv.x; d[1][0] = bv.y; d[1][1] = bv.y;
    }
#pragma unroll 2
    for (int ig = 0; ig < 16; ++ig) {
        const float4 x0 = *(const float4*)&xls[0][s][ig * 4];   // x2@7
        const float4 x1 = *(const float4*)&xls[1][s][ig * 4];   // x2@9
        const float4 x2 = *(const float4*)&xls[7][s][ig * 4];   // x2@11
#pragma unroll
        for (int oo = 0; oo < 2; ++oo) {
            const float4* wp = oo ? w1p : w0p;
            const float4 wA = wp[64 + ig * 2 + 0];
            const float4 wB = wp[64 + ig * 2 + 1];
            float t0 = d[oo][0], t1 = d[oo][1];
            t0 = fmaf(wA.x, x0.x, t0);  t0 = fmaf(wA.y, x1.x, t0);
            t0 = fmaf(wA.z, x0.y, t0);  t0 = fmaf(wA.w, x1.y, t0);
            t0 = fmaf(wB.x, x0.z, t0);  t0 = fmaf(wB.y, x1.z, t0);
            t0 = fmaf(wB.z, x0.w, t0);  t0 = fmaf(wB.w, x1.w, t0);
            t1 = fmaf(wA.x, x1.x, t1);  t1 = fmaf(wA.y, x2.x, t1);
            t1 = fmaf(wA.z, x1.y, t1);  t1 = fmaf(wA.w, x2.y, t1);
            t1 = fmaf(wB.x, x1.z, t1);  t1 = fmaf(wB.y, x2.z, t1);
            t1 = fmaf(wB.z, x1.w, t1);  t1 = fmaf(wB.w, x2.w, t1);
            d[oo][0] = t0; d[oo][1] = t1;
        }
    }
    // y3 -> slots {3,8} (y1 dead; stage-3 reads only {0,1,7})
    {
        float2 o2;
        o2.x = fmaxf(d[0][0], 0.f); o2.y = fmaxf(d[1][0], 0.f);
        *(float2*)&xls[3][s][obase] = o2;                // y3@9
        o2.x = fmaxf(d[0][1], 0.f); o2.y = fmaxf(d[1][1], 0.f);
        *(float2*)&xls[8][s][obase] = o2;                // y3@11
    }
    __syncthreads();

    // ---- stage 4: l1 conv2 (D=2) at t=11; y3 slots {3,8}  (c=3: 96..127)
    float f[2];
    {
        const float2 bv = *(const float2*)(tb2 + 64 + obase);
        f[0] = bv.x; f[1] = bv.y;
    }
#pragma unroll 2
    for (int ig = 0; ig < 16; ++ig) {
        const float4 g0 = *(const float4*)&xls[3][s][ig * 4];   // y3@9
        const float4 g1 = *(const float4*)&xls[8][s][ig * 4];   // y3@11
#pragma unroll
        for (int oo = 0; oo < 2; ++oo) {
            const float4* wp = oo ? w1p : w0p;
            const float4 wA = wp[96 + ig * 2 + 0];
            const float4 wB = wp[96 + ig * 2 + 1];
            float t0 = f[oo];
            t0 = fmaf(wA.x, g0.x, t0);  t0 = fmaf(wA.y, g1.x, t0);
            t0 = fmaf(wA.z, g0.y, t0);  t0 = fmaf(wA.w, g1.y, t0);
            t0 = fmaf(wB.x, g0.z, t0);  t0 = fmaf(wB.y, g1.z, t0);
            t0 = fmaf(wB.z, g0.w, t0);  t0 = fmaf(wB.w, g1.w, t0);
            f[oo] = t0;
        }
    }
    // ht = relu(relu(f) + x2@11)
    float ht[2];
    {
        const float2 xr = *(const float2*)&xls[7][s][obase];
        ht[0] = fmaxf(fmaxf(f[0], 0.f) + xr.x, 0.f);
        ht[1] = fmaxf(fmaxf(f[1], 0.f) + xr.y, 0.f);
    }

    // ---- epilogue: gate (cross-hg shfl strides 8..32 + cross-wave LDS)
    float* pbuf = &xls[2][0][0];                         // slot 2 free now
    {
        const float2 wg2 = *(const float2*)(wgate + obase);
        float p = ht[0] * wg2.x + ht[1] * wg2.y;
        p += __shfl_xor(p, 8); p += __shfl_xor(p, 16); p += __shfl_xor(p, 32);
        if (hg == 0) pbuf[wfl * 8 + s] = p;
    }
    __syncthreads();
    float ptot = 0.f;
#pragma unroll
    for (int w4i = 0; w4i < 4; ++w4i) ptot += pbuf[w4i * 8 + s];
    const float g = 1.f / (1.f + expf(-(ptot + bgate[0])));
    float fo[2];
    {
        const float2 hs = *(const float2*)&xls[6][s][obase];   // x1@11
        fo[0] = g * ht[0] + (1.f - g) * hs.x;
        fo[1] = g * ht[1] + (1.f - g) * hs.y;
    }
    float po[12];
#pragma unroll
    for (int h2 = 0; h2 < 12; ++h2) po[h2] = 0.f;
#pragma unroll
    for (int oo = 0; oo < 2; ++oo) {
        const float* wr = wout + (obase + oo) * 12;
        const float4 w0 = *(const float4*)(wr);
        const float4 w1 = *(const float4*)(wr + 4);
        const float4 w2 = *(const float4*)(wr + 8);
        po[0] = fmaf(fo[oo], w0.x, po[0]);  po[1] = fmaf(fo[oo], w0.y, po[1]);
        po[2] = fmaf(fo[oo], w0.z, po[2]);  po[3] = fmaf(fo[oo], w0.w, po[3]);
        po[4] = fmaf(fo[oo], w1.x, po[4]);  po[5] = fmaf(fo[oo], w1.y, po[5]);
        po[6] = fmaf(fo[oo], w1.z, po[6]);  po[7] = fmaf(fo[oo], w1.w, po[7]);
        po[8] = fmaf(fo[oo], w2.x, po[8]);  po[9] = fmaf(fo[oo], w2.y, po[9]);
        po[10] = fmaf(fo[oo], w2.z, po[10]); po[11] = fmaf(fo[oo], w2.w, po[11]);
    }
#pragma unroll
    for (int h2 = 0; h2 < 12; ++h2) {
        po[h2] += __shfl_xor(po[h2], 8);
        po[h2] += __shfl_xor(po[h2], 16);
        po[h2] += __shfl_xor(po[h2], 32);
    }
    float* pobuf = &xls[4][0][0];                        // slots 4-5 free (1088 f)
    if (hg == 0) {
#pragma unroll
        for (int h2 = 0; h2 < 12; ++h2)
            pobuf[(wfl * 12 + h2) * 8 + s] = po[h2];
    }
    __syncthreads();
    if (tid < 96) {
        const int h2 = tid >> 3, sq = tid & 7;
        float r = bout[h2];
#pragma unroll
        for (int w4i = 0; w4i < 4; ++w4i)
            r += pobuf[(w4i * 12 + h2) * 8 + sq];
        outp[h2 * 8000 + bI * 2000 + n0 + sq] = r;
    }
}

extern "C" void kernel_launch(void* const* d_in, const int* in_sizes, int n_in,
                              void* d_out, int out_size, void* d_ws, size_t ws_size,
                              hipStream_t stream) {
    const float* inputs     = (const float*)d_in[0];
    const float* node_feas  = (const float*)d_in[1];
    const int*   node_index = (const int*)  d_in[2];
    const float* w_fc3 = (const float*)d_in[3];
    const float* b_fc3 = (const float*)d_in[4];
    const float* w_fc4 = (const float*)d_in[5];
    const float* b_fc4 = (const float*)d_in[6];
    const float* w_fc5 = (const float*)d_in[7];
    const float* b_fc5 = (const float*)d_in[8];
    const float* w_nhp = (const float*)d_in[9];
    const float* b_nhp = (const float*)d_in[10];
    const float* w_q   = (const float*)d_in[11];
    const float* w_k   = (const float*)d_in[12];
    const float* w_in  = (const float*)d_in[13];
    const float* b_in  = (const float*)d_in[14];
    const float* sws   = (const float*)d_in[15];
    const float* sbs   = (const float*)d_in[16];
    const float* swn   = (const float*)d_in[17];
    const float* sbn   = (const float*)d_in[18];
    const float* tw1   = (const float*)d_in[19];
    const float* tb1   = (const float*)d_in[20];
    const float* tw2   = (const float*)d_in[21];
    const float* tb2   = (const float*)d_in[22];
    const float* wgate = (const float*)d_in[23];
    const float* bgate = (const float*)d_in[24];
    const float* wout  = (const float*)d_in[25];
    const float* bout  = (const float*)d_in[26];

    float* out  = (float*)d_out;           // (12,4,2000)        96000
    float* mid  = out + 96000;             // (4,12,2000,64)     6144000
    float* wadj = mid + 6144000;           // (2000,32)          64000

    float*  q     = (float*)d_ws;          // 128000
    float*  ek    = q     + 128000;        // 128000
    float*  nh2   = ek    + 128000;        // 128000 (includes b_nhp + b_in)
    float*  base1 = nh2   + 128000;        // 128000
    float*  xT    = base1 + 128000;        // 96000   [n][bt]
    float2* xa    = (float2*)(xT + 96000); // 96000 float2 {x, ax}
    float*  vecs  = xT + 96000 + 192000;   // 128 {s1v, n1v}
    float2* W2    = (float2*)(vecs + 128); // 16384 float2 (TCN weights [o][c][ig])
    float4* wsg   = (float4*)(vecs + 128 + 32768);  // 4096 float4 (SAGE packed)

    k_embed<<<500, 256, 0, stream>>>(node_feas, inputs, w_fc3, b_fc3, w_fc4, b_fc4,
                                     w_fc5, b_fc5, w_q, w_k, w_nhp, b_nhp, b_in,
                                     tw1, tw2, sws, swn, W2, wsg,
                                     q, ek, nh2, xT);
    k_front<<<501, 256, 0, stream>>>(q, ek, xT, nh2, node_index,
                                     sws, sbs, swn, sbn, w_in, wsg,
                                     wadj, xa, base1, vecs);
    k_sage2<<<2000, 512, 0, stream>>>(base1, xa, vecs, node_index, wadj,
                                      wsg + 2048, sbs, sbn, mid);
    k_tcn<<<1000, 256, 0, stream>>>(mid, W2, tb1, tb2,
                                    wgate, bgate, wout, bout, out);
}